// Round 10
// baseline (1412.781 us; speedup 1.0000x reference)
//
#include <hip/hip_runtime.h>
#include <hip/hip_bf16.h>

typedef __hip_bfloat16 bf16;

// Problem constants
static constexpr int Nn = 2, CIN = 128, Hh = 240, Ww = 320, HW = 76800;
static constexpr int Cc = 128, HID = 512, DOUT = 256, WSQ = 49;
static constexpr int NWH = 35, NWW = 46, WPN = NWH * NWW;   // 1610 windows per image
static constexpr int NWIN = Nn * WPN;                        // 3220
static constexpr float SCALE = 0.17677669529663687f;         // 32^-0.5

// attn LDS geometry (v3): 4 head slices + xw/vT region = 25,856 shorts = 51,712 B
static constexpr int SLICE = 4160;   // shorts per head slice (q[52][40], k @2080)
static constexpr int KOFF  = 2080;
static constexpr int TRIM  = 52;     // q/k rows stored; >=49 masked downstream
static constexpr int XWOFF = 16640;  // 4*SLICE

typedef __attribute__((ext_vector_type(8))) short s8;   // 8 bf16 = one MFMA A/B frag
typedef __attribute__((ext_vector_type(4))) short s4;   // packed 4-bf16 LDS write
typedef __attribute__((ext_vector_type(2))) short s2;
typedef __attribute__((ext_vector_type(4))) float f4;   // MFMA accumulator

__device__ __forceinline__ short f2bf(float x) {
  union { bf16 b; short s; } u; u.b = __float2bfloat16(x); return u.s;
}

// tanh-form gelu via HW exp (see R8 notes).
__device__ __forceinline__ float gelu_f(float x) {
  const float u = 0.7978845608028654f * fmaf(0.044715f * x, x * x, x);
  const float e = __expf(2.f * u);
  const float t = fmaf(-2.f, __frcp_rn(e + 1.f), 1.f);   // tanh(u)
  return 0.5f * x * (1.f + t);
}

#define MFMA(a, b, c) __builtin_amdgcn_mfma_f32_16x16x32_bf16((a), (b), (c), 0, 0, 0)

// ---------------- weight cast: f32 -> bf16 (once per launch) ----------------
__global__ __launch_bounds__(256) void cast_bf16(const float* __restrict__ src,
                                                 short* __restrict__ dst, int n) {
  const int i = (blockIdx.x * 256 + threadIdx.x) * 4;
  if (i < n) {
    const float4 v = *(const float4*)(src + i);
    s4 o; o[0] = f2bf(v.x); o[1] = f2bf(v.y); o[2] = f2bf(v.z); o[3] = f2bf(v.w);
    *(s4*)(dst + i) = o;
  }
}

__global__ void init_head(float* headbuf) {
  if (threadIdx.x < 256) headbuf[threadIdx.x] = 0.f;
}

// ---------------- conv_w transpose: wT[c][e] = conv_w[e][c] (once) ----------------
__global__ __launch_bounds__(256) void transp_w(const float* __restrict__ conv_w,
                                                float* __restrict__ wT) {
  const int idx = blockIdx.x * 256 + threadIdx.x;   // 16384 total
  const int c = idx >> 7, e = idx & 127;
  wT[c * 128 + e] = conv_w[e * 128 + c];
}

// ---------------- 1x1 conv -> residual stream tok[n,hw,e] (f32, in d_out) ----------------
// v5: depth-4 x-prefetch + 16 KB LDS chunks. No forced min-occupancy.
__global__ __launch_bounds__(256) void conv_kernel(
    const float* __restrict__ x, const float* __restrict__ wT, const float* __restrict__ conv_b,
    float* __restrict__ tok) {
  __shared__ float wlds[32 * 128];  // [c-chunk][e], 16 KB
  const int tid = threadIdx.x;
  const int lane = tid & 63, w = tid >> 6;
  const int n = blockIdx.y;
  const int hw0 = blockIdx.x * 128;
  const int hwi = 2 * lane;         // thread owns hw pair (hwi, hwi+1)
  const int e0 = 32 * w;            // wave owns 32-wide e slice
  const float* xn = x + (size_t)n * CIN * HW + hw0 + hwi;
  float acc[2][32];
#pragma unroll
  for (int jj = 0; jj < 8; jj++) {
    const float4 b4 = *(const float4*)(conv_b + e0 + jj * 4);
    acc[0][jj*4+0] = b4.x; acc[1][jj*4+0] = b4.x;
    acc[0][jj*4+1] = b4.y; acc[1][jj*4+1] = b4.y;
    acc[0][jj*4+2] = b4.z; acc[1][jj*4+2] = b4.z;
    acc[0][jj*4+3] = b4.w; acc[1][jj*4+3] = b4.w;
  }
  float2 xv[4];
#pragma unroll
  for (int j = 0; j < 4; j++) xv[j] = *(const float2*)(xn + (size_t)j * HW);
  for (int ch = 0; ch < 4; ch++) {
    if (ch) __syncthreads();        // all waves done reading previous chunk
    for (int idx = tid * 4; idx < 4096; idx += 1024)
      *(float4*)(wlds + idx) = *(const float4*)(wT + ch * 4096 + idx);
    __syncthreads();
    for (int cg = 0; cg < 32; cg += 4) {
      float2 nx[4];
#pragma unroll
      for (int j = 0; j < 4; j++) {
        int cn = ch * 32 + cg + 4 + j;          // prefetch next group (may cross chunk)
        if (cn > 127) cn = 127;                 // tail clamp: dummy valid load
        nx[j] = *(const float2*)(xn + (size_t)cn * HW);
      }
#pragma unroll
      for (int j = 0; j < 4; j++) {
        const float* wl = wlds + (cg + j) * 128 + e0;
#pragma unroll
        for (int jj = 0; jj < 8; jj++) {
          const float4 w4 = *(const float4*)(wl + jj * 4);
          acc[0][jj*4+0] = fmaf(w4.x, xv[j].x, acc[0][jj*4+0]); acc[1][jj*4+0] = fmaf(w4.x, xv[j].y, acc[1][jj*4+0]);
          acc[0][jj*4+1] = fmaf(w4.y, xv[j].x, acc[0][jj*4+1]); acc[1][jj*4+1] = fmaf(w4.y, xv[j].y, acc[1][jj*4+1]);
          acc[0][jj*4+2] = fmaf(w4.z, xv[j].x, acc[0][jj*4+2]); acc[1][jj*4+2] = fmaf(w4.z, xv[j].y, acc[1][jj*4+2]);
          acc[0][jj*4+3] = fmaf(w4.w, xv[j].x, acc[0][jj*4+3]); acc[1][jj*4+3] = fmaf(w4.w, xv[j].y, acc[1][jj*4+3]);
        }
      }
#pragma unroll
      for (int j = 0; j < 4; j++) xv[j] = nx[j];
    }
  }
  float* tb0 = tok + ((size_t)n * HW + hw0 + hwi) * Cc + e0;
  float* tb1 = tb0 + Cc;
#pragma unroll
  for (int jj = 0; jj < 8; jj++) {
    *(float4*)(tb0 + jj * 4) = make_float4(acc[0][jj*4], acc[0][jj*4+1], acc[0][jj*4+2], acc[0][jj*4+3]);
    *(float4*)(tb1 + jj * 4) = make_float4(acc[1][jj*4], acc[1][jj*4+1], acc[1][jj*4+2], acc[1][jj*4+3]);
  }
}

// ---------------- fused window attention v3 (see R6 notes) ----------------
__global__ __launch_bounds__(256, 2) void attn_kernel(
    float* __restrict__ tok,
    const float* __restrict__ n1_g, const float* __restrict__ n1_b,
    const short* __restrict__ wqkv, const float* __restrict__ qkv_b,
    const short* __restrict__ wproj, const float* __restrict__ proj_b,
    int layer) {
  __shared__ __align__(16) short ms[25856];
  short* xwv = ms + XWOFF;

  const int tid = threadIdx.x;
  const int w = tid >> 6, lane = tid & 63;
  const int lq = lane >> 4, li = lane & 15;
  const int wi = blockIdx.x;
  const int n = wi / WPN;
  const int r0 = wi % WPN;
  const int wh = r0 / NWW, ww = r0 % NWW;

  const short* wqkv_l = wqkv + (size_t)layer * 384 * 128;
  const short* wproj_l = wproj + (size_t)layer * 128 * 128;

  // ---- Phase 1a: coalesced gather -> g32 f32 [49][128] (slice region) ----
  {
    float* g32 = (float*)ms;
    for (int idx = tid; idx < WSQ * 32; idx += 256) {
      const int t = idx >> 5, c4 = (idx & 31) * 4;
      const int hh = wh * 7 + t / 7, wv = ww * 7 + t % 7;
      float4 v = make_float4(0.f, 0.f, 0.f, 0.f);
      if (hh < Hh && wv < Ww)
        v = *(const float4*)(tok + ((size_t)n * HW + hh * Ww + wv) * Cc + c4);
      *(float4*)(g32 + t * 128 + c4) = v;
    }
    for (int idx = tid; idx < 15 * 136; idx += 256)
      xwv[(49 + idx / 136) * 136 + (idx % 136)] = 0;
    __syncthreads();
    // ---- Phase 1b: LayerNorm from LDS -> xw bf16 [64][136] ----
    for (int ti = w; ti < WSQ; ti += 4) {
      const int hh = wh * 7 + ti / 7, wv = ww * 7 + ti % 7;
      const bool valid = (hh < Hh) && (wv < Ww);
      const float2 v = *(const float2*)(g32 + ti * 128 + 2 * lane);
      float s = v.x + v.y, q = v.x * v.x + v.y * v.y;
#pragma unroll
      for (int m = 1; m < 64; m <<= 1) { s += __shfl_xor(s, m); q += __shfl_xor(q, m); }
      const float mean = s * (1.f / 128.f);
      const float rstd = rsqrtf(fmaxf(q * (1.f / 128.f) - mean * mean, 0.f) + 1e-5f);
      const int c = 2 * lane;
      float o0 = 0.f, o1 = 0.f;
      if (valid) {
        o0 = (v.x - mean) * rstd * n1_g[layer * Cc + c]     + n1_b[layer * Cc + c];
        o1 = (v.y - mean) * rstd * n1_g[layer * Cc + c + 1] + n1_b[layer * Cc + c + 1];
      }
      s2 pk; pk[0] = f2bf(o0); pk[1] = f2bf(o1);
      *(s2*)(xwv + ti * 136 + c) = pk;
    }
  }
  __syncthreads();   // g32 consumed; slices may now be overwritten by q/k

  // ---- Phase 2a: q,k transposed: D'[n][token] = wqkv . xw^T ----
  {
    const int n0 = 64 * w;
    f4 acc[4][4];
#pragma unroll
    for (int mt = 0; mt < 4; mt++)
#pragma unroll
      for (int nt = 0; nt < 4; nt++) acc[mt][nt] = f4{0.f, 0.f, 0.f, 0.f};
    for (int s = 0; s < 4; s++) {
      s8 a[4], b[4];
#pragma unroll
      for (int mt = 0; mt < 4; mt++)
        a[mt] = *(const s8*)(wqkv_l + (n0 + mt * 16 + li) * 128 + s * 32 + lq * 8);
#pragma unroll
      for (int nt = 0; nt < 4; nt++)
        b[nt] = *(const s8*)(xwv + (nt * 16 + li) * 136 + s * 32 + lq * 8);
#pragma unroll
      for (int mt = 0; mt < 4; mt++)
#pragma unroll
        for (int nt = 0; nt < 4; nt++) acc[mt][nt] = MFMA(a[mt], b[nt], acc[mt][nt]);
    }
    const bool isq = (w < 2);
    const float scl = isq ? SCALE : 1.f;
    const int koff = isq ? 0 : KOFF;
#pragma unroll
    for (int mt = 0; mt < 4; mt++) {
      const int nbase = n0 + mt * 16 + lq * 4;            // qkv output row (r=0)
      const int hsel = (isq ? nbase : (nbase - 128)) >> 5;
      const int d0 = nbase & 31;
      const float4 bb = *(const float4*)(qkv_b + layer * 384 + nbase);
#pragma unroll
      for (int nt = 0; nt < 4; nt++) {
        const int tokn = nt * 16 + li;
        if (tokn < TRIM) {   // rows >= TRIM trimmed (masked downstream)
          s4 pk;
          pk[0] = f2bf((acc[mt][nt][0] + bb.x) * scl);
          pk[1] = f2bf((acc[mt][nt][1] + bb.y) * scl);
          pk[2] = f2bf((acc[mt][nt][2] + bb.z) * scl);
          pk[3] = f2bf((acc[mt][nt][3] + bb.w) * scl);
          *(s4*)(ms + hsel * SLICE + koff + tokn * 40 + d0) = pk;
        }
      }
    }
  }

  // ---- Phase 2b: v straight: D[token][n] = xw . wqkv_v^T ; export vT[d][token] ----
  {
    const int n0v = 32 * w;
    f4 acc2[4][2];
#pragma unroll
    for (int mt = 0; mt < 4; mt++)
#pragma unroll
      for (int nt = 0; nt < 2; nt++) acc2[mt][nt] = f4{0.f, 0.f, 0.f, 0.f};
    for (int s = 0; s < 4; s++) {
      s8 a[4], b[2];
#pragma unroll
      for (int mt = 0; mt < 4; mt++)
        a[mt] = *(const s8*)(xwv + (mt * 16 + li) * 136 + s * 32 + lq * 8);
#pragma unroll
      for (int nt = 0; nt < 2; nt++)
        b[nt] = *(const s8*)(wqkv_l + (256 + n0v + nt * 16 + li) * 128 + s * 32 + lq * 8);
#pragma unroll
      for (int mt = 0; mt < 4; mt++)
#pragma unroll
        for (int nt = 0; nt < 2; nt++) acc2[mt][nt] = MFMA(a[mt], b[nt], acc2[mt][nt]);
    }
    __syncthreads();  // all xw reads + all q/k writes complete
#pragma unroll
    for (int nt = 0; nt < 2; nt++) {
      const int d = n0v + nt * 16 + li;
      const float bv = qkv_b[layer * 384 + 256 + d];
#pragma unroll
      for (int mt = 0; mt < 4; mt++) {
        const int m0 = mt * 16 + lq * 4;
        s4 pk;
        pk[0] = f2bf(acc2[mt][nt][0] + bv);
        pk[1] = f2bf(acc2[mt][nt][1] + bv);
        pk[2] = f2bf(acc2[mt][nt][2] + bv);
        pk[3] = f2bf(acc2[mt][nt][3] + bv);
        *(s4*)(xwv + d * 72 + m0) = pk;
      }
    }
  }

  // ---- Phase 3: per-head (wave = head): S^T = K.Q^T -> softmax -> O^T = V^T.P^T ----
  {
    short* qbase = ms + w * SLICE;
    short* kbase = qbase + KOFF;
    s8 ak[4], bq[4];
#pragma unroll
    for (int kt = 0; kt < 4; kt++) ak[kt] = *(const s8*)(kbase + (kt * 16 + li) * 40 + lq * 8);
#pragma unroll
    for (int qt = 0; qt < 4; qt++) bq[qt] = *(const s8*)(qbase + (qt * 16 + li) * 40 + lq * 8);
    f4 sc[4][4];
#pragma unroll
    for (int kt = 0; kt < 4; kt++)
#pragma unroll
      for (int qt = 0; qt < 4; qt++) sc[kt][qt] = f4{0.f, 0.f, 0.f, 0.f};
#pragma unroll
    for (int kt = 0; kt < 4; kt++)
#pragma unroll
      for (int qt = 0; qt < 4; qt++) sc[kt][qt] = MFMA(ak[kt], bq[qt], sc[kt][qt]);
#pragma unroll
    for (int kt = 0; kt < 4; kt++)
#pragma unroll
      for (int r = 0; r < 4; r++)
        if (kt * 16 + lq * 4 + r >= WSQ) {
#pragma unroll
          for (int qt = 0; qt < 4; qt++) sc[kt][qt][r] = -1e30f;
        }
    float inv[4];
#pragma unroll
    for (int qt = 0; qt < 4; qt++) {
      float m = -1e30f;
#pragma unroll
      for (int kt = 0; kt < 4; kt++)
#pragma unroll
        for (int r = 0; r < 4; r++) m = fmaxf(m, sc[kt][qt][r]);
      m = fmaxf(m, __shfl_xor(m, 16));
      m = fmaxf(m, __shfl_xor(m, 32));
      float ssum = 0.f;
#pragma unroll
      for (int kt = 0; kt < 4; kt++)
#pragma unroll
        for (int r = 0; r < 4; r++) {
          const float e = __expf(sc[kt][qt][r] - m);
          sc[kt][qt][r] = e; ssum += e;
        }
      ssum += __shfl_xor(ssum, 16);
      ssum += __shfl_xor(ssum, 32);
      inv[qt] = 1.f / ssum;
    }
#pragma unroll
    for (int qt = 0; qt < 4; qt++) {
      const int qq = qt * 16 + li;
      if (qq < TRIM) {
#pragma unroll
        for (int kt = 0; kt < 4; kt++) {
          s4 pk;
          pk[0] = f2bf(sc[kt][qt][0] * inv[qt]);
          pk[1] = f2bf(sc[kt][qt][1] * inv[qt]);
          pk[2] = f2bf(sc[kt][qt][2] * inv[qt]);
          pk[3] = f2bf(sc[kt][qt][3] * inv[qt]);
          *(s4*)(qbase + qq * 72 + kt * 16 + lq * 4) = pk;
        }
      }
    }
    f4 ov[2][4];
#pragma unroll
    for (int dt = 0; dt < 2; dt++)
#pragma unroll
      for (int qt = 0; qt < 4; qt++) ov[dt][qt] = f4{0.f, 0.f, 0.f, 0.f};
    for (int s = 0; s < 2; s++) {
      s8 av[2], bp[4];
#pragma unroll
      for (int dt = 0; dt < 2; dt++)
        av[dt] = *(const s8*)(xwv + (w * 32 + dt * 16 + li) * 72 + s * 32 + lq * 8);
#pragma unroll
      for (int qt = 0; qt < 4; qt++)
        bp[qt] = *(const s8*)(qbase + (qt * 16 + li) * 72 + s * 32 + lq * 8);
#pragma unroll
      for (int dt = 0; dt < 2; dt++)
#pragma unroll
        for (int qt = 0; qt < 4; qt++) ov[dt][qt] = MFMA(av[dt], bp[qt], ov[dt][qt]);
    }
    short* ohb = qbase;
#pragma unroll
    for (int dt = 0; dt < 2; dt++) {
      const int dl0 = dt * 16 + lq * 4;
#pragma unroll
      for (int qt = 0; qt < 4; qt++) {
        const int tokn = qt * 16 + li;
        s4 pk;
        pk[0] = f2bf(ov[dt][qt][0]);
        pk[1] = f2bf(ov[dt][qt][1]);
        pk[2] = f2bf(ov[dt][qt][2]);
        pk[3] = f2bf(ov[dt][qt][3]);
        *(s4*)(ohb + tokn * 40 + dl0) = pk;
      }
    }
  }
  __syncthreads();

  // ---- Phase 4: proj straight: D[token][c] = o . wproj^T ; staged residual RMW ----
  {
    const int n0p = 32 * w;
    f4 pa[4][2];
#pragma unroll
    for (int mt = 0; mt < 4; mt++)
#pragma unroll
      for (int nt = 0; nt < 2; nt++) pa[mt][nt] = f4{0.f, 0.f, 0.f, 0.f};
    for (int s = 0; s < 4; s++) {
      s8 ao[4], bw[2];
#pragma unroll
      for (int mt = 0; mt < 4; mt++)
        ao[mt] = *(const s8*)(ms + s * SLICE + (mt * 16 + li) * 40 + lq * 8);
#pragma unroll
      for (int nt = 0; nt < 2; nt++)
        bw[nt] = *(const s8*)(wproj_l + (n0p + nt * 16 + li) * 128 + s * 32 + lq * 8);
#pragma unroll
      for (int mt = 0; mt < 4; mt++)
#pragma unroll
        for (int nt = 0; nt < 2; nt++) pa[mt][nt] = MFMA(ao[mt], bw[nt], pa[mt][nt]);
    }
    __syncthreads();  // all o reads done everywhere; ms fully dead -> res
    float* res = (float*)ms;   // [64][132] f32 = 33,792 B
#pragma unroll
    for (int nt = 0; nt < 2; nt++) {
      const int c = n0p + nt * 16 + li;
#pragma unroll
      for (int mt = 0; mt < 4; mt++) {
#pragma unroll
        for (int r = 0; r < 4; r++) {
          const int m = mt * 16 + lq * 4 + r;
          res[m * 132 + c] = pa[mt][nt][r];
        }
      }
    }
    __syncthreads();
    for (int idx = tid; idx < WSQ * 32; idx += 256) {
      const int t = idx >> 5, c4 = (idx & 31) * 4;
      const int hh = wh * 7 + t / 7, wv = ww * 7 + t % 7;
      if (hh < Hh && wv < Ww) {
        float* p = tok + ((size_t)n * HW + hh * Ww + wv) * Cc + c4;
        const float4 g = *(const float4*)p;
        const float4 r4 = *(const float4*)(res + t * 132 + c4);
        const float4 pb4 = *(const float4*)(proj_b + layer * 128 + c4);
        *(float4*)p = make_float4(g.x + r4.x + pb4.x, g.y + r4.y + pb4.y,
                                  g.z + r4.z + pb4.z, g.w + r4.w + pb4.w);
      }
    }
  }
}

// ---------------- fused MLP v5: 64 tok/block + quad-LN + weight prefetch ----------------
// v3 (64t) = 144 us, VALUBusy 50% (~72 us pure VALU issue), Occ ~28%. v4
// (128t) regressed (150 us, Occ 18.5) -> tile size is a dead lever; occupancy
// levers exhausted (R5/R8). v5 reverts to v3 geometry and cuts the measured
// VALU + exposed-latency terms: (a) quad-group LN: lane-quad owns one token's
// 128 ch, 2 shfl_xor -> 1 pass instead of 16 full-wave passes (~600 -> ~230
// inst/wave); (b) fc1 AND fc2 a-fragments prefetched into registers at round
// start, BEFORE the barriers (read-only loads; compiler won't hoist across
// __syncthreads itself) -> L2 latency lands under fc1-MFMA+gelu. VGPR ~170
// expected; tripwire: VGPR>=256 or WRITE_SIZE balloon => spilled, revert.
__global__ __launch_bounds__(256) void mlp_kernel(
    float* __restrict__ tok,
    const float* __restrict__ n2_g, const float* __restrict__ n2_b,
    const short* __restrict__ wfc1, const float* __restrict__ fc1_b,
    const short* __restrict__ wfc2, const float* __restrict__ fc2_b,
    int layer) {
  __shared__ __align__(16) short lnb[64 * 136];   // LN'd tokens bf16 [64][136]
  __shared__ __align__(16) short hbuf[64 * 136];  // hid slice bf16 [tok][128], single

  const int tid = threadIdx.x;
  const int w = tid >> 6, lane = tid & 63;
  const int lq = lane >> 4, li = lane & 15;
  const int t0 = blockIdx.x * 64;
  const short* wfc1_l = wfc1 + (size_t)layer * 512 * 128;
  const short* wfc2_l = wfc2 + (size_t)layer * 128 * 512;

  // ---- Phase 1: quad-group LN, one pass: lane-quad owns one token ----
  {
    const int qd = lane >> 2;          // 0..15 -> token within wave's 16
    const int e  = lane & 3;           // channel quarter [32e, 32e+32)
    const int tl = w * 16 + qd;
    const float* tp = tok + (size_t)(t0 + tl) * Cc + e * 32;
    float4 v[8];
#pragma unroll
    for (int j = 0; j < 8; j++) v[j] = *(const float4*)(tp + j * 4);
    float s = 0.f, q = 0.f;
#pragma unroll
    for (int j = 0; j < 8; j++) {
      s += v[j].x + v[j].y + v[j].z + v[j].w;
      q = fmaf(v[j].x, v[j].x, q); q = fmaf(v[j].y, v[j].y, q);
      q = fmaf(v[j].z, v[j].z, q); q = fmaf(v[j].w, v[j].w, q);
    }
    s += __shfl_xor(s, 1); s += __shfl_xor(s, 2);
    q += __shfl_xor(q, 1); q += __shfl_xor(q, 2);
    const float mean = s * (1.f / 128.f);
    const float rstd = rsqrtf(fmaxf(q * (1.f / 128.f) - mean * mean, 0.f) + 1e-5f);
    const float* gp = n2_g + layer * Cc + e * 32;
    const float* bp = n2_b + layer * Cc + e * 32;
#pragma unroll
    for (int j = 0; j < 8; j++) {
      const float4 g4 = *(const float4*)(gp + j * 4);
      const float4 b4 = *(const float4*)(bp + j * 4);
      s4 pk;
      pk[0] = f2bf((v[j].x - mean) * rstd * g4.x + b4.x);
      pk[1] = f2bf((v[j].y - mean) * rstd * g4.y + b4.y);
      pk[2] = f2bf((v[j].z - mean) * rstd * g4.z + b4.z);
      pk[3] = f2bf((v[j].w - mean) * rstd * g4.w + b4.w);
      *(s4*)(lnb + tl * 136 + e * 32 + j * 4) = pk;
    }
  }
  __syncthreads();

  f4 acc2[2][4];
#pragma unroll
  for (int mt = 0; mt < 2; mt++)
#pragma unroll
    for (int nt = 0; nt < 4; nt++) acc2[mt][nt] = f4{0.f, 0.f, 0.f, 0.f};
  const int c0 = 32 * w;

  for (int s = 0; s < 4; s++) {
    const int hbase = 128 * s + 32 * w;   // wave w's 32 h-rows this round
    // ---- prefetch this round's fc1 + fc2 weight fragments (read-only) ----
    s8 wa1[2][4], wa2[2][4];
#pragma unroll
    for (int mt = 0; mt < 2; mt++)
#pragma unroll
      for (int kc = 0; kc < 4; kc++) {
        wa1[mt][kc] = *(const s8*)(wfc1_l + (hbase + mt * 16 + li) * 128 + kc * 32 + lq * 8);
        wa2[mt][kc] = *(const s8*)(wfc2_l + (c0 + mt * 16 + li) * 512 + s * 128 + kc * 32 + lq * 8);
      }
    // ---- fc1 ----
    f4 acc1[2][4];
#pragma unroll
    for (int mt = 0; mt < 2; mt++)
#pragma unroll
      for (int nt = 0; nt < 4; nt++) acc1[mt][nt] = f4{0.f, 0.f, 0.f, 0.f};
    for (int kc = 0; kc < 4; kc++) {
      s8 b[4];
#pragma unroll
      for (int nt = 0; nt < 4; nt++)
        b[nt] = *(const s8*)(lnb + (nt * 16 + li) * 136 + kc * 32 + lq * 8);
#pragma unroll
      for (int mt = 0; mt < 2; mt++)
#pragma unroll
        for (int nt = 0; nt < 4; nt++) acc1[mt][nt] = MFMA(wa1[mt][kc], b[nt], acc1[mt][nt]);
    }
    if (s) __syncthreads();   // all waves' fc2 reads of hbuf (round s-1) done
#pragma unroll
    for (int mt = 0; mt < 2; mt++) {
      const int hl0 = 32 * w + mt * 16 + lq * 4;       // h_local in [0,128)
      const float4 bb = *(const float4*)(fc1_b + layer * HID + 128 * s + hl0);
#pragma unroll
      for (int nt = 0; nt < 4; nt++) {
        const int tokn = nt * 16 + li;
        s4 pk;
        pk[0] = f2bf(gelu_f(acc1[mt][nt][0] + bb.x));
        pk[1] = f2bf(gelu_f(acc1[mt][nt][1] + bb.y));
        pk[2] = f2bf(gelu_f(acc1[mt][nt][2] + bb.z));
        pk[3] = f2bf(gelu_f(acc1[mt][nt][3] + bb.w));
        *(s4*)(hbuf + tokn * 136 + hl0) = pk;
      }
    }
    __syncthreads();  // hbuf complete
    // ---- fc2 partial (weights already in registers) ----
    for (int kc = 0; kc < 4; kc++) {
      s8 b[4];
#pragma unroll
      for (int nt = 0; nt < 4; nt++)
        b[nt] = *(const s8*)(hbuf + (nt * 16 + li) * 136 + kc * 32 + lq * 8);
#pragma unroll
      for (int mt = 0; mt < 2; mt++)
#pragma unroll
        for (int nt = 0; nt < 4; nt++) acc2[mt][nt] = MFMA(wa2[mt][kc], b[nt], acc2[mt][nt]);
    }
  }

#pragma unroll
  for (int mt = 0; mt < 2; mt++) {
    const int cb = c0 + mt * 16 + lq * 4;
    const float4 bb = *(const float4*)(fc2_b + layer * Cc + cb);
#pragma unroll
    for (int nt = 0; nt < 4; nt++) {
      const int tokn = nt * 16 + li;
      float* p = tok + (size_t)(t0 + tokn) * Cc + cb;
      const float4 g = *(const float4*)p;
      *(float4*)p = make_float4(g.x + acc2[mt][nt][0] + bb.x,
                                g.y + acc2[mt][nt][1] + bb.y,
                                g.z + acc2[mt][nt][2] + bb.z,
                                g.w + acc2[mt][nt][3] + bb.w);
    }
  }
}

// ---------------- head mean ----------------
__global__ __launch_bounds__(256) void head_kernel(const float* __restrict__ tok,
                                                   float* __restrict__ headbuf) {
  const int n = blockIdx.x >> 6, slice = blockIdx.x & 63;
  const int c = threadIdx.x & 127, half = threadIdx.x >> 7;
  const float* base = tok + ((size_t)n * HW + slice * 1200 + half * 600) * Cc + c;
  float s = 0.f;
  for (int i = 0; i < 600; i++) s += base[(size_t)i * Cc];
  atomicAdd(&headbuf[n * 128 + c], s * (1.f / 76800.f));
}

// ---------------- y head MLP ----------------
__global__ __launch_bounds__(256) void y_kernel(
    const float* __restrict__ headbuf,
    const float* __restrict__ r1_w, const float* __restrict__ r1_b,
    const float* __restrict__ r2_w, const float* __restrict__ r2_b,
    const float* __restrict__ r3_w, const float* __restrict__ r3_b,
    float* __restrict__ yout) {
  __shared__ float hb[128], y1[256], y2[256], red4[4];
  const int tid = threadIdx.x;
  const int n = blockIdx.x;
  if (tid < 128) hb[tid] = headbuf[n * 128 + tid];
  __syncthreads();
  {
    float s = r1_b[tid];
    const float* w = r1_w + (size_t)tid * 128;
    for (int c = 0; c < 128; c += 4) {
      const float4 w4 = *(const float4*)(w + c);
      s = fmaf(w4.x, hb[c], s); s = fmaf(w4.y, hb[c+1], s);
      s = fmaf(w4.z, hb[c+2], s); s = fmaf(w4.w, hb[c+3], s);
    }
    y1[tid] = s >= 0.f ? s : 0.01f * s;
  }
  __syncthreads();
  {
    float s = r2_b[tid];
    const float* w = r2_w + (size_t)tid * 256;
    for (int c = 0; c < 256; c += 4) {
      const float4 w4 = *(const float4*)(w + c);
      s = fmaf(w4.x, y1[c], s); s = fmaf(w4.y, y1[c+1], s);
      s = fmaf(w4.z, y1[c+2], s); s = fmaf(w4.w, y1[c+3], s);
    }
    y2[tid] = s >= 0.f ? s : 0.01f * s;
  }
  __syncthreads();
  float v;
  {
    float s = r3_b[tid];
    const float* w = r3_w + (size_t)tid * 256;
    for (int c = 0; c < 256; c += 4) {
      const float4 w4 = *(const float4*)(w + c);
      s = fmaf(w4.x, y2[c], s); s = fmaf(w4.y, y2[c+1], s);
      s = fmaf(w4.z, y2[c+2], s); s = fmaf(w4.w, y2[c+3], s);
    }
    v = (s > 0.f ? s : 0.f) + 0.1f;
  }
  float t = v;
#pragma unroll
  for (int m = 1; m < 64; m <<= 1) t += __shfl_xor(t, m);
  if ((tid & 63) == 0) red4[tid >> 6] = t;
  __syncthreads();
  const float tot = red4[0] + red4[1] + red4[2] + red4[3];
  yout[n * DOUT + tid] = v / tot;
}

// ---------------- maps prep: fold queries into conv weights ----------------
__global__ __launch_bounds__(256) void qprep_kernel(
    const float* __restrict__ tok, const float* __restrict__ conv_w, const float* __restrict__ conv_b,
    float* __restrict__ qwx, float* __restrict__ qb) {
  __shared__ float qs[16 * 128];  // [q_local][e]
  const int tid = threadIdx.x;
  const int n = blockIdx.x >> 3, g = blockIdx.x & 7;
  const int q0 = g * 16;
  for (int idx = tid; idx < 2048; idx += 256)
    qs[idx] = tok[((size_t)n * HW + q0 + (idx >> 7)) * Cc + (idx & 127)];
  __syncthreads();
  const int c = tid & 127, half = tid >> 7;
  float acc[8];
#pragma unroll
  for (int j = 0; j < 8; j++) acc[j] = 0.f;
  for (int e = 0; e < 128; e += 4) {
    const float w0 = conv_w[(e + 0) * 128 + c];
    const float w1 = conv_w[(e + 1) * 128 + c];
    const float w2 = conv_w[(e + 2) * 128 + c];
    const float w3 = conv_w[(e + 3) * 128 + c];
#pragma unroll
    for (int j = 0; j < 8; j++) {
      const float4 qv = *(const float4*)(qs + (half * 8 + j) * 128 + e);
      acc[j] = fmaf(qv.x, w0, fmaf(qv.y, w1, fmaf(qv.z, w2, fmaf(qv.w, w3, acc[j]))));
    }
  }
  float* dst = qwx + ((size_t)n * 128 + c) * 128 + q0 + half * 8;
#pragma unroll
  for (int j = 0; j < 8; j++) dst[j] = acc[j];
  if (tid < 16) {
    float s = 0.f;
    for (int e = 0; e < 128; e += 4) {
      const float4 qv = *(const float4*)(qs + tid * 128 + e);
      const float4 bv = *(const float4*)(conv_b + e);
      s = fmaf(qv.x, bv.x, fmaf(qv.y, bv.y, fmaf(qv.z, bv.z, fmaf(qv.w, bv.w, s))));
    }
    qb[n * 128 + q0 + tid] = s;
  }
}

// ---------------- maps v4: conv v5 structure (depth-4 prefetch, 16 KB chunks) ----------------
__global__ __launch_bounds__(256) void maps_kernel(
    const float* __restrict__ x, const float* __restrict__ qwx, const float* __restrict__ qb,
    float* __restrict__ mout) {
  __shared__ float qlds[32 * 128];  // [c-chunk][q], 16 KB
  const int tid = threadIdx.x;
  const int lane = tid & 63, w = tid >> 6;
  const int n = blockIdx.y;
  const int hw0 = blockIdx.x * 128;
  const int hwi = 2 * lane;
  const int q0 = 32 * w;
  const float* xn = x + (size_t)n * CIN * HW + hw0 + hwi;
  float acc[2][32];
#pragma unroll
  for (int jj = 0; jj < 8; jj++) {
    const float4 b4 = *(const float4*)(qb + n * 128 + q0 + jj * 4);
    acc[0][jj*4+0] = b4.x; acc[1][jj*4+0] = b4.x;
    acc[0][jj*4+1] = b4.y; acc[1][jj*4+1] = b4.y;
    acc[0][jj*4+2] = b4.z; acc[1][jj*4+2] = b4.z;
    acc[0][jj*4+3] = b4.w; acc[1][jj*4+3] = b4.w;
  }
  float2 xv[4];
#pragma unroll
  for (int j = 0; j < 4; j++) xv[j] = *(const float2*)(xn + (size_t)j * HW);
  for (int ch = 0; ch < 4; ch++) {
    if (ch) __syncthreads();
    for (int idx = tid * 4; idx < 4096; idx += 1024)
      *(float4*)(qlds + idx) = *(const float4*)(qwx + (size_t)n * 16384 + ch * 4096 + idx);
    __syncthreads();
    for (int cg = 0; cg < 32; cg += 4) {
      float2 nx[4];
#pragma unroll
      for (int j = 0; j < 4; j++) {
        int cn = ch * 32 + cg + 4 + j;
        if (cn > 127) cn = 127;
        nx[j] = *(const float2*)(xn + (size_t)cn * HW);
      }
#pragma unroll
      for (int j = 0; j < 4; j++) {
        const float* ql = qlds + (cg + j) * 128 + q0;
#pragma unroll
        for (int jj = 0; jj < 8; jj++) {
          const float4 w4 = *(const float4*)(ql + jj * 4);
          acc[0][jj*4+0] = fmaf(w4.x, xv[j].x, acc[0][jj*4+0]); acc[1][jj*4+0] = fmaf(w4.x, xv[j].y, acc[1][jj*4+0]);
          acc[0][jj*4+1] = fmaf(w4.y, xv[j].x, acc[0][jj*4+1]); acc[1][jj*4+1] = fmaf(w4.y, xv[j].y, acc[1][jj*4+1]);
          acc[0][jj*4+2] = fmaf(w4.z, xv[j].x, acc[0][jj*4+2]); acc[1][jj*4+2] = fmaf(w4.z, xv[j].y, acc[1][jj*4+2]);
          acc[0][jj*4+3] = fmaf(w4.w, xv[j].x, acc[0][jj*4+3]); acc[1][jj*4+3] = fmaf(w4.w, xv[j].y, acc[1][jj*4+3]);
        }
      }
#pragma unroll
      for (int j = 0; j < 4; j++) xv[j] = nx[j];
    }
  }
  float* mb = mout + ((size_t)n * 128 + q0) * HW + hw0 + hwi;
#pragma unroll
  for (int jj = 0; jj < 32; jj++) {
    *(float2*)(mb + (size_t)jj * HW) = make_float2(acc[0][jj], acc[1][jj]);
  }
}

extern "C" void kernel_launch(void* const* d_in, const int* in_sizes, int n_in,
                              void* d_out, int out_size, void* d_ws, size_t ws_size,
                              hipStream_t stream) {
  const float* x      = (const float*)d_in[0];
  const float* conv_w = (const float*)d_in[1];
  const float* conv_b = (const float*)d_in[2];
  const float* n1_g   = (const float*)d_in[3];
  const float* n1_b   = (const float*)d_in[4];
  const float* qkv_w  = (const float*)d_in[5];
  const float* qkv_b  = (const float*)d_in[6];
  const float* proj_w = (const float*)d_in[7];
  const float* proj_b = (const float*)d_in[8];
  const float* n2_g   = (const float*)d_in[9];
  const float* n2_b   = (const float*)d_in[10];
  const float* fc1_w  = (const float*)d_in[11];
  const float* fc1_b  = (const float*)d_in[12];
  const float* fc2_w  = (const float*)d_in[13];
  const float* fc2_b  = (const float*)d_in[14];
  const float* r1_w   = (const float*)d_in[15];
  const float* r1_b   = (const float*)d_in[16];
  const float* r2_w   = (const float*)d_in[17];
  const float* r2_b   = (const float*)d_in[18];
  const float* r3_w   = (const float*)d_in[19];
  const float* r3_b   = (const float*)d_in[20];

  // Token residual stream (f32) lives in the d_out maps region; consumed before maps.
  float* out = (float*)d_out;
  float* tok = out + 512;

  // ws: bf16 weight copies (1.57 MB) + qwx/qb/headbuf
  char* ws = (char*)d_ws;
  short* wqkv = (short*)ws;                       // 4*384*128
  short* wproj = (short*)(ws + 393216);           // 4*128*128
  short* wfc1 = (short*)(ws + 524288);            // 4*512*128
  short* wfc2 = (short*)(ws + 1048576);           // 4*128*512
  float* qwx = (float*)(ws + 1572864);            // 2*128*128 f32
  float* qb = (float*)(ws + 1703936);             // 2*128
  float* headbuf = (float*)(ws + 1704960);        // 2*128
  // wconvT aliases the qwx region: used only by conv (early); qwx written by
  // qprep (late). 128*128 f32 = 64 KB <= qwx's 128 KB.
  float* wconvT = qwx;

  cast_bf16<<<196608 / 1024, 256, 0, stream>>>(qkv_w, wqkv, 196608);
  cast_bf16<<<65536 / 1024, 256, 0, stream>>>(proj_w, wproj, 65536);
  cast_bf16<<<262144 / 1024, 256, 0, stream>>>(fc1_w, wfc1, 262144);
  cast_bf16<<<262144 / 1024, 256, 0, stream>>>(fc2_w, wfc2, 262144);
  init_head<<<1, 256, 0, stream>>>(headbuf);
  transp_w<<<64, 256, 0, stream>>>(conv_w, wconvT);
  conv_kernel<<<dim3(600, 2), 256, 0, stream>>>(x, wconvT, conv_b, tok);
  for (int l = 0; l < 4; l++) {
    attn_kernel<<<NWIN, 256, 0, stream>>>(tok, n1_g, n1_b, wqkv, qkv_b, wproj, proj_b, l);
    mlp_kernel<<<2400, 256, 0, stream>>>(tok, n2_g, n2_b, wfc1, fc1_b, wfc2, fc2_b, l);
  }
  head_kernel<<<128, 256, 0, stream>>>(tok, headbuf);
  y_kernel<<<2, 256, 0, stream>>>(headbuf, r1_w, r1_b, r2_w, r2_b, r3_w, r3_b, out);
  qprep_kernel<<<16, 256, 0, stream>>>(tok, conv_w, conv_b, qwx, qb);
  maps_kernel<<<dim3(600, 2), 256, 0, stream>>>(x, qwx, qb, out + 512);
}

// Round 11
// 1336.740 us; speedup vs baseline: 1.0569x; 1.0569x over previous
//
#include <hip/hip_runtime.h>
#include <hip/hip_bf16.h>

typedef __hip_bfloat16 bf16;

// Problem constants
static constexpr int Nn = 2, CIN = 128, Hh = 240, Ww = 320, HW = 76800;
static constexpr int Cc = 128, HID = 512, DOUT = 256, WSQ = 49;
static constexpr int NWH = 35, NWW = 46, WPN = NWH * NWW;   // 1610 windows per image
static constexpr int NWIN = Nn * WPN;                        // 3220
static constexpr float SCALE = 0.17677669529663687f;         // 32^-0.5

// attn LDS geometry (v3): 4 head slices + xw/vT region = 25,856 shorts = 51,712 B
static constexpr int SLICE = 4160;   // shorts per head slice (q[52][40], k @2080)
static constexpr int KOFF  = 2080;
static constexpr int TRIM  = 52;     // q/k rows stored; >=49 masked downstream
static constexpr int XWOFF = 16640;  // 4*SLICE

typedef __attribute__((ext_vector_type(8))) short s8;   // 8 bf16 = one MFMA A/B frag
typedef __attribute__((ext_vector_type(4))) short s4;   // packed 4-bf16 LDS write
typedef __attribute__((ext_vector_type(2))) short s2;
typedef __attribute__((ext_vector_type(4))) float f4;   // MFMA accumulator

__device__ __forceinline__ short f2bf(float x) {
  union { bf16 b; short s; } u; u.b = __float2bfloat16(x); return u.s;
}

// tanh-form gelu via HW exp: ~8 VALU ops vs erff's ~20+. Numerics validated
// R8-R10 (absmax 0.03125 unchanged). Applied here to the v2 mlp structure
// (R8 bundled it with the single-buffer change, which independently regressed).
__device__ __forceinline__ float gelu_f(float x) {
  const float u = 0.7978845608028654f * fmaf(0.044715f * x, x * x, x);
  const float e = __expf(2.f * u);
  const float t = fmaf(-2.f, __frcp_rn(e + 1.f), 1.f);   // tanh(u)
  return 0.5f * x * (1.f + t);
}

#define MFMA(a, b, c) __builtin_amdgcn_mfma_f32_16x16x32_bf16((a), (b), (c), 0, 0, 0)

// ---------------- weight cast: f32 -> bf16 (once per launch) ----------------
__global__ __launch_bounds__(256) void cast_bf16(const float* __restrict__ src,
                                                 short* __restrict__ dst, int n) {
  const int i = (blockIdx.x * 256 + threadIdx.x) * 4;
  if (i < n) {
    const float4 v = *(const float4*)(src + i);
    s4 o; o[0] = f2bf(v.x); o[1] = f2bf(v.y); o[2] = f2bf(v.z); o[3] = f2bf(v.w);
    *(s4*)(dst + i) = o;
  }
}

__global__ void init_head(float* headbuf) {
  if (threadIdx.x < 256) headbuf[threadIdx.x] = 0.f;
}

// ---------------- conv_w transpose: wT[c][e] = conv_w[e][c] (once) ----------------
__global__ __launch_bounds__(256) void transp_w(const float* __restrict__ conv_w,
                                                float* __restrict__ wT) {
  const int idx = blockIdx.x * 256 + threadIdx.x;   // 16384 total
  const int c = idx >> 7, e = idx & 127;
  wT[c * 128 + e] = conv_w[e * 128 + c];
}

// ---------------- 1x1 conv -> residual stream tok[n,hw,e] (f32, in d_out) ----------------
// v5: depth-4 x-prefetch + 16 KB LDS chunks. No forced min-occupancy.
__global__ __launch_bounds__(256) void conv_kernel(
    const float* __restrict__ x, const float* __restrict__ wT, const float* __restrict__ conv_b,
    float* __restrict__ tok) {
  __shared__ float wlds[32 * 128];  // [c-chunk][e], 16 KB
  const int tid = threadIdx.x;
  const int lane = tid & 63, w = tid >> 6;
  const int n = blockIdx.y;
  const int hw0 = blockIdx.x * 128;
  const int hwi = 2 * lane;         // thread owns hw pair (hwi, hwi+1)
  const int e0 = 32 * w;            // wave owns 32-wide e slice
  const float* xn = x + (size_t)n * CIN * HW + hw0 + hwi;
  float acc[2][32];
#pragma unroll
  for (int jj = 0; jj < 8; jj++) {
    const float4 b4 = *(const float4*)(conv_b + e0 + jj * 4);
    acc[0][jj*4+0] = b4.x; acc[1][jj*4+0] = b4.x;
    acc[0][jj*4+1] = b4.y; acc[1][jj*4+1] = b4.y;
    acc[0][jj*4+2] = b4.z; acc[1][jj*4+2] = b4.z;
    acc[0][jj*4+3] = b4.w; acc[1][jj*4+3] = b4.w;
  }
  float2 xv[4];
#pragma unroll
  for (int j = 0; j < 4; j++) xv[j] = *(const float2*)(xn + (size_t)j * HW);
  for (int ch = 0; ch < 4; ch++) {
    if (ch) __syncthreads();        // all waves done reading previous chunk
    for (int idx = tid * 4; idx < 4096; idx += 1024)
      *(float4*)(wlds + idx) = *(const float4*)(wT + ch * 4096 + idx);
    __syncthreads();
    for (int cg = 0; cg < 32; cg += 4) {
      float2 nx[4];
#pragma unroll
      for (int j = 0; j < 4; j++) {
        int cn = ch * 32 + cg + 4 + j;          // prefetch next group (may cross chunk)
        if (cn > 127) cn = 127;                 // tail clamp: dummy valid load
        nx[j] = *(const float2*)(xn + (size_t)cn * HW);
      }
#pragma unroll
      for (int j = 0; j < 4; j++) {
        const float* wl = wlds + (cg + j) * 128 + e0;
#pragma unroll
        for (int jj = 0; jj < 8; jj++) {
          const float4 w4 = *(const float4*)(wl + jj * 4);
          acc[0][jj*4+0] = fmaf(w4.x, xv[j].x, acc[0][jj*4+0]); acc[1][jj*4+0] = fmaf(w4.x, xv[j].y, acc[1][jj*4+0]);
          acc[0][jj*4+1] = fmaf(w4.y, xv[j].x, acc[0][jj*4+1]); acc[1][jj*4+1] = fmaf(w4.y, xv[j].y, acc[1][jj*4+1]);
          acc[0][jj*4+2] = fmaf(w4.z, xv[j].x, acc[0][jj*4+2]); acc[1][jj*4+2] = fmaf(w4.z, xv[j].y, acc[1][jj*4+2]);
          acc[0][jj*4+3] = fmaf(w4.w, xv[j].x, acc[0][jj*4+3]); acc[1][jj*4+3] = fmaf(w4.w, xv[j].y, acc[1][jj*4+3]);
        }
      }
#pragma unroll
      for (int j = 0; j < 4; j++) xv[j] = nx[j];
    }
  }
  float* tb0 = tok + ((size_t)n * HW + hw0 + hwi) * Cc + e0;
  float* tb1 = tb0 + Cc;
#pragma unroll
  for (int jj = 0; jj < 8; jj++) {
    *(float4*)(tb0 + jj * 4) = make_float4(acc[0][jj*4], acc[0][jj*4+1], acc[0][jj*4+2], acc[0][jj*4+3]);
    *(float4*)(tb1 + jj * 4) = make_float4(acc[1][jj*4], acc[1][jj*4+1], acc[1][jj*4+2], acc[1][jj*4+3]);
  }
}

// ---------------- fused window attention v3 (see R6 notes) ----------------
__global__ __launch_bounds__(256, 2) void attn_kernel(
    float* __restrict__ tok,
    const float* __restrict__ n1_g, const float* __restrict__ n1_b,
    const short* __restrict__ wqkv, const float* __restrict__ qkv_b,
    const short* __restrict__ wproj, const float* __restrict__ proj_b,
    int layer) {
  __shared__ __align__(16) short ms[25856];
  short* xwv = ms + XWOFF;

  const int tid = threadIdx.x;
  const int w = tid >> 6, lane = tid & 63;
  const int lq = lane >> 4, li = lane & 15;
  const int wi = blockIdx.x;
  const int n = wi / WPN;
  const int r0 = wi % WPN;
  const int wh = r0 / NWW, ww = r0 % NWW;

  const short* wqkv_l = wqkv + (size_t)layer * 384 * 128;
  const short* wproj_l = wproj + (size_t)layer * 128 * 128;

  // ---- Phase 1a: coalesced gather -> g32 f32 [49][128] (slice region) ----
  {
    float* g32 = (float*)ms;
    for (int idx = tid; idx < WSQ * 32; idx += 256) {
      const int t = idx >> 5, c4 = (idx & 31) * 4;
      const int hh = wh * 7 + t / 7, wv = ww * 7 + t % 7;
      float4 v = make_float4(0.f, 0.f, 0.f, 0.f);
      if (hh < Hh && wv < Ww)
        v = *(const float4*)(tok + ((size_t)n * HW + hh * Ww + wv) * Cc + c4);
      *(float4*)(g32 + t * 128 + c4) = v;
    }
    for (int idx = tid; idx < 15 * 136; idx += 256)
      xwv[(49 + idx / 136) * 136 + (idx % 136)] = 0;
    __syncthreads();
    // ---- Phase 1b: LayerNorm from LDS -> xw bf16 [64][136] ----
    for (int ti = w; ti < WSQ; ti += 4) {
      const int hh = wh * 7 + ti / 7, wv = ww * 7 + ti % 7;
      const bool valid = (hh < Hh) && (wv < Ww);
      const float2 v = *(const float2*)(g32 + ti * 128 + 2 * lane);
      float s = v.x + v.y, q = v.x * v.x + v.y * v.y;
#pragma unroll
      for (int m = 1; m < 64; m <<= 1) { s += __shfl_xor(s, m); q += __shfl_xor(q, m); }
      const float mean = s * (1.f / 128.f);
      const float rstd = rsqrtf(fmaxf(q * (1.f / 128.f) - mean * mean, 0.f) + 1e-5f);
      const int c = 2 * lane;
      float o0 = 0.f, o1 = 0.f;
      if (valid) {
        o0 = (v.x - mean) * rstd * n1_g[layer * Cc + c]     + n1_b[layer * Cc + c];
        o1 = (v.y - mean) * rstd * n1_g[layer * Cc + c + 1] + n1_b[layer * Cc + c + 1];
      }
      s2 pk; pk[0] = f2bf(o0); pk[1] = f2bf(o1);
      *(s2*)(xwv + ti * 136 + c) = pk;
    }
  }
  __syncthreads();   // g32 consumed; slices may now be overwritten by q/k

  // ---- Phase 2a: q,k transposed: D'[n][token] = wqkv . xw^T ----
  {
    const int n0 = 64 * w;
    f4 acc[4][4];
#pragma unroll
    for (int mt = 0; mt < 4; mt++)
#pragma unroll
      for (int nt = 0; nt < 4; nt++) acc[mt][nt] = f4{0.f, 0.f, 0.f, 0.f};
    for (int s = 0; s < 4; s++) {
      s8 a[4], b[4];
#pragma unroll
      for (int mt = 0; mt < 4; mt++)
        a[mt] = *(const s8*)(wqkv_l + (n0 + mt * 16 + li) * 128 + s * 32 + lq * 8);
#pragma unroll
      for (int nt = 0; nt < 4; nt++)
        b[nt] = *(const s8*)(xwv + (nt * 16 + li) * 136 + s * 32 + lq * 8);
#pragma unroll
      for (int mt = 0; mt < 4; mt++)
#pragma unroll
        for (int nt = 0; nt < 4; nt++) acc[mt][nt] = MFMA(a[mt], b[nt], acc[mt][nt]);
    }
    const bool isq = (w < 2);
    const float scl = isq ? SCALE : 1.f;
    const int koff = isq ? 0 : KOFF;
#pragma unroll
    for (int mt = 0; mt < 4; mt++) {
      const int nbase = n0 + mt * 16 + lq * 4;            // qkv output row (r=0)
      const int hsel = (isq ? nbase : (nbase - 128)) >> 5;
      const int d0 = nbase & 31;
      const float4 bb = *(const float4*)(qkv_b + layer * 384 + nbase);
#pragma unroll
      for (int nt = 0; nt < 4; nt++) {
        const int tokn = nt * 16 + li;
        if (tokn < TRIM) {   // rows >= TRIM trimmed (masked downstream)
          s4 pk;
          pk[0] = f2bf((acc[mt][nt][0] + bb.x) * scl);
          pk[1] = f2bf((acc[mt][nt][1] + bb.y) * scl);
          pk[2] = f2bf((acc[mt][nt][2] + bb.z) * scl);
          pk[3] = f2bf((acc[mt][nt][3] + bb.w) * scl);
          *(s4*)(ms + hsel * SLICE + koff + tokn * 40 + d0) = pk;
        }
      }
    }
  }

  // ---- Phase 2b: v straight: D[token][n] = xw . wqkv_v^T ; export vT[d][token] ----
  {
    const int n0v = 32 * w;
    f4 acc2[4][2];
#pragma unroll
    for (int mt = 0; mt < 4; mt++)
#pragma unroll
      for (int nt = 0; nt < 2; nt++) acc2[mt][nt] = f4{0.f, 0.f, 0.f, 0.f};
    for (int s = 0; s < 4; s++) {
      s8 a[4], b[2];
#pragma unroll
      for (int mt = 0; mt < 4; mt++)
        a[mt] = *(const s8*)(xwv + (mt * 16 + li) * 136 + s * 32 + lq * 8);
#pragma unroll
      for (int nt = 0; nt < 2; nt++)
        b[nt] = *(const s8*)(wqkv_l + (256 + n0v + nt * 16 + li) * 128 + s * 32 + lq * 8);
#pragma unroll
      for (int mt = 0; mt < 4; mt++)
#pragma unroll
        for (int nt = 0; nt < 2; nt++) acc2[mt][nt] = MFMA(a[mt], b[nt], acc2[mt][nt]);
    }
    __syncthreads();  // all xw reads + all q/k writes complete
#pragma unroll
    for (int nt = 0; nt < 2; nt++) {
      const int d = n0v + nt * 16 + li;
      const float bv = qkv_b[layer * 384 + 256 + d];
#pragma unroll
      for (int mt = 0; mt < 4; mt++) {
        const int m0 = mt * 16 + lq * 4;
        s4 pk;
        pk[0] = f2bf(acc2[mt][nt][0] + bv);
        pk[1] = f2bf(acc2[mt][nt][1] + bv);
        pk[2] = f2bf(acc2[mt][nt][2] + bv);
        pk[3] = f2bf(acc2[mt][nt][3] + bv);
        *(s4*)(xwv + d * 72 + m0) = pk;
      }
    }
  }

  // ---- Phase 3: per-head (wave = head): S^T = K.Q^T -> softmax -> O^T = V^T.P^T ----
  {
    short* qbase = ms + w * SLICE;
    short* kbase = qbase + KOFF;
    s8 ak[4], bq[4];
#pragma unroll
    for (int kt = 0; kt < 4; kt++) ak[kt] = *(const s8*)(kbase + (kt * 16 + li) * 40 + lq * 8);
#pragma unroll
    for (int qt = 0; qt < 4; qt++) bq[qt] = *(const s8*)(qbase + (qt * 16 + li) * 40 + lq * 8);
    f4 sc[4][4];
#pragma unroll
    for (int kt = 0; kt < 4; kt++)
#pragma unroll
      for (int qt = 0; qt < 4; qt++) sc[kt][qt] = f4{0.f, 0.f, 0.f, 0.f};
#pragma unroll
    for (int kt = 0; kt < 4; kt++)
#pragma unroll
      for (int qt = 0; qt < 4; qt++) sc[kt][qt] = MFMA(ak[kt], bq[qt], sc[kt][qt]);
#pragma unroll
    for (int kt = 0; kt < 4; kt++)
#pragma unroll
      for (int r = 0; r < 4; r++)
        if (kt * 16 + lq * 4 + r >= WSQ) {
#pragma unroll
          for (int qt = 0; qt < 4; qt++) sc[kt][qt][r] = -1e30f;
        }
    float inv[4];
#pragma unroll
    for (int qt = 0; qt < 4; qt++) {
      float m = -1e30f;
#pragma unroll
      for (int kt = 0; kt < 4; kt++)
#pragma unroll
        for (int r = 0; r < 4; r++) m = fmaxf(m, sc[kt][qt][r]);
      m = fmaxf(m, __shfl_xor(m, 16));
      m = fmaxf(m, __shfl_xor(m, 32));
      float ssum = 0.f;
#pragma unroll
      for (int kt = 0; kt < 4; kt++)
#pragma unroll
        for (int r = 0; r < 4; r++) {
          const float e = __expf(sc[kt][qt][r] - m);
          sc[kt][qt][r] = e; ssum += e;
        }
      ssum += __shfl_xor(ssum, 16);
      ssum += __shfl_xor(ssum, 32);
      inv[qt] = 1.f / ssum;
    }
#pragma unroll
    for (int qt = 0; qt < 4; qt++) {
      const int qq = qt * 16 + li;
      if (qq < TRIM) {
#pragma unroll
        for (int kt = 0; kt < 4; kt++) {
          s4 pk;
          pk[0] = f2bf(sc[kt][qt][0] * inv[qt]);
          pk[1] = f2bf(sc[kt][qt][1] * inv[qt]);
          pk[2] = f2bf(sc[kt][qt][2] * inv[qt]);
          pk[3] = f2bf(sc[kt][qt][3] * inv[qt]);
          *(s4*)(qbase + qq * 72 + kt * 16 + lq * 4) = pk;
        }
      }
    }
    f4 ov[2][4];
#pragma unroll
    for (int dt = 0; dt < 2; dt++)
#pragma unroll
      for (int qt = 0; qt < 4; qt++) ov[dt][qt] = f4{0.f, 0.f, 0.f, 0.f};
    for (int s = 0; s < 2; s++) {
      s8 av[2], bp[4];
#pragma unroll
      for (int dt = 0; dt < 2; dt++)
        av[dt] = *(const s8*)(xwv + (w * 32 + dt * 16 + li) * 72 + s * 32 + lq * 8);
#pragma unroll
      for (int qt = 0; qt < 4; qt++)
        bp[qt] = *(const s8*)(qbase + (qt * 16 + li) * 72 + s * 32 + lq * 8);
#pragma unroll
      for (int dt = 0; dt < 2; dt++)
#pragma unroll
        for (int qt = 0; qt < 4; qt++) ov[dt][qt] = MFMA(av[dt], bp[qt], ov[dt][qt]);
    }
    short* ohb = qbase;
#pragma unroll
    for (int dt = 0; dt < 2; dt++) {
      const int dl0 = dt * 16 + lq * 4;
#pragma unroll
      for (int qt = 0; qt < 4; qt++) {
        const int tokn = qt * 16 + li;
        s4 pk;
        pk[0] = f2bf(ov[dt][qt][0]);
        pk[1] = f2bf(ov[dt][qt][1]);
        pk[2] = f2bf(ov[dt][qt][2]);
        pk[3] = f2bf(ov[dt][qt][3]);
        *(s4*)(ohb + tokn * 40 + dl0) = pk;
      }
    }
  }
  __syncthreads();

  // ---- Phase 4: proj straight: D[token][c] = o . wproj^T ; staged residual RMW ----
  {
    const int n0p = 32 * w;
    f4 pa[4][2];
#pragma unroll
    for (int mt = 0; mt < 4; mt++)
#pragma unroll
      for (int nt = 0; nt < 2; nt++) pa[mt][nt] = f4{0.f, 0.f, 0.f, 0.f};
    for (int s = 0; s < 4; s++) {
      s8 ao[4], bw[2];
#pragma unroll
      for (int mt = 0; mt < 4; mt++)
        ao[mt] = *(const s8*)(ms + s * SLICE + (mt * 16 + li) * 40 + lq * 8);
#pragma unroll
      for (int nt = 0; nt < 2; nt++)
        bw[nt] = *(const s8*)(wproj_l + (n0p + nt * 16 + li) * 128 + s * 32 + lq * 8);
#pragma unroll
      for (int mt = 0; mt < 4; mt++)
#pragma unroll
        for (int nt = 0; nt < 2; nt++) pa[mt][nt] = MFMA(ao[mt], bw[nt], pa[mt][nt]);
    }
    __syncthreads();  // all o reads done everywhere; ms fully dead -> res
    float* res = (float*)ms;   // [64][132] f32 = 33,792 B
#pragma unroll
    for (int nt = 0; nt < 2; nt++) {
      const int c = n0p + nt * 16 + li;
#pragma unroll
      for (int mt = 0; mt < 4; mt++) {
#pragma unroll
        for (int r = 0; r < 4; r++) {
          const int m = mt * 16 + lq * 4 + r;
          res[m * 132 + c] = pa[mt][nt][r];
        }
      }
    }
    __syncthreads();
    for (int idx = tid; idx < WSQ * 32; idx += 256) {
      const int t = idx >> 5, c4 = (idx & 31) * 4;
      const int hh = wh * 7 + t / 7, wv = ww * 7 + t % 7;
      if (hh < Hh && wv < Ww) {
        float* p = tok + ((size_t)n * HW + hh * Ww + wv) * Cc + c4;
        const float4 g = *(const float4*)p;
        const float4 r4 = *(const float4*)(res + t * 132 + c4);
        const float4 pb4 = *(const float4*)(proj_b + layer * 128 + c4);
        *(float4*)p = make_float4(g.x + r4.x + pb4.x, g.y + r4.y + pb4.y,
                                  g.z + r4.z + pb4.z, g.w + r4.w + pb4.w);
      }
    }
  }
}

// ---------------- fused MLP v6 = v2 (R7 best, 64 tok dbuf) + fast gelu ----------------
// v2 measured 141.8 us in the best total (R7, 1283.9). v3/v4/v5 all regressed
// (single-buf +extra barrier, 128-tok occupancy drop, prefetch defeated by
// regalloc). v6 = exact v2 structure with the ONLY independently-safe change:
// erff (~20 ops x 128 calls/wave) -> tanh-form gelu (~8 ops).
__global__ __launch_bounds__(256, 3) void mlp_kernel(
    float* __restrict__ tok,
    const float* __restrict__ n2_g, const float* __restrict__ n2_b,
    const short* __restrict__ wfc1, const float* __restrict__ fc1_b,
    const short* __restrict__ wfc2, const float* __restrict__ fc2_b,
    int layer) {
  __shared__ __align__(16) short lnb[64 * 136];      // LN'd tokens bf16 [64][136]
  __shared__ __align__(16) short hbuf[2][64 * 136];  // hid slice bf16 [tok][128] (dbuf)

  const int tid = threadIdx.x;
  const int w = tid >> 6, lane = tid & 63;
  const int lq = lane >> 4, li = lane & 15;
  const int t0 = blockIdx.x * 64;
  const short* wfc1_l = wfc1 + (size_t)layer * 512 * 128;
  const short* wfc2_l = wfc2 + (size_t)layer * 128 * 512;

  // ---- Phase 1: LN -> lnb bf16 (wave w owns tokens [16w,16w+16)) ----
#pragma unroll
  for (int i = 0; i < 16; i++) {
    const int tl = w * 16 + i;
    const float2 v = *(const float2*)(tok + (size_t)(t0 + tl) * Cc + 2 * lane);
    float s = v.x + v.y, q = v.x * v.x + v.y * v.y;
#pragma unroll
    for (int m = 1; m < 64; m <<= 1) { s += __shfl_xor(s, m); q += __shfl_xor(q, m); }
    const float mean = s * (1.f / 128.f);
    const float rstd = rsqrtf(fmaxf(q * (1.f / 128.f) - mean * mean, 0.f) + 1e-5f);
    const int c = 2 * lane;
    s2 pk;
    pk[0] = f2bf((v.x - mean) * rstd * n2_g[layer * Cc + c]     + n2_b[layer * Cc + c]);
    pk[1] = f2bf((v.y - mean) * rstd * n2_g[layer * Cc + c + 1] + n2_b[layer * Cc + c + 1]);
    *(s2*)(lnb + tl * 136 + c) = pk;
  }
  __syncthreads();

  // fc2 output accumulators: wave w owns c-rows [32w,32w+32), all 64 tokens.
  f4 acc2[2][4];
#pragma unroll
  for (int mt = 0; mt < 2; mt++)
#pragma unroll
    for (int nt = 0; nt < 4; nt++) acc2[mt][nt] = f4{0.f, 0.f, 0.f, 0.f};
  const int c0 = 32 * w;

  // ---- Rounds: fc1 h-slice [128s,128s+128) -> gelu -> hbuf -> fc2 partial ----
  for (int s = 0; s < 4; s++) {
    f4 acc1[2][4];
#pragma unroll
    for (int mt = 0; mt < 2; mt++)
#pragma unroll
      for (int nt = 0; nt < 4; nt++) acc1[mt][nt] = f4{0.f, 0.f, 0.f, 0.f};
    const int hbase = 128 * s + 32 * w;   // wave w's 32 h-rows this round
    for (int kc = 0; kc < 4; kc++) {
      s8 a[2], b[4];
#pragma unroll
      for (int mt = 0; mt < 2; mt++)
        a[mt] = *(const s8*)(wfc1_l + (hbase + mt * 16 + li) * 128 + kc * 32 + lq * 8);
#pragma unroll
      for (int nt = 0; nt < 4; nt++)
        b[nt] = *(const s8*)(lnb + (nt * 16 + li) * 136 + kc * 32 + lq * 8);
#pragma unroll
      for (int mt = 0; mt < 2; mt++)
#pragma unroll
        for (int nt = 0; nt < 4; nt++) acc1[mt][nt] = MFMA(a[mt], b[nt], acc1[mt][nt]);
    }
    short* hb = hbuf[s & 1];
#pragma unroll
    for (int mt = 0; mt < 2; mt++) {
      const int hl0 = 32 * w + mt * 16 + lq * 4;       // h_local in [0,128)
      const float4 bb = *(const float4*)(fc1_b + layer * HID + 128 * s + hl0);
#pragma unroll
      for (int nt = 0; nt < 4; nt++) {
        const int tokn = nt * 16 + li;
        s4 pk;
        pk[0] = f2bf(gelu_f(acc1[mt][nt][0] + bb.x));
        pk[1] = f2bf(gelu_f(acc1[mt][nt][1] + bb.y));
        pk[2] = f2bf(gelu_f(acc1[mt][nt][2] + bb.z));
        pk[3] = f2bf(gelu_f(acc1[mt][nt][3] + bb.w));
        *(s4*)(hb + tokn * 136 + hl0) = pk;
      }
    }
    __syncthreads();  // hbuf[s&1] complete; safe vs round s+2 by barrier s+1
    for (int kc = 0; kc < 4; kc++) {
      s8 a[2], b[4];
#pragma unroll
      for (int mt = 0; mt < 2; mt++)
        a[mt] = *(const s8*)(wfc2_l + (c0 + mt * 16 + li) * 512 + s * 128 + kc * 32 + lq * 8);
#pragma unroll
      for (int nt = 0; nt < 4; nt++)
        b[nt] = *(const s8*)(hb + (nt * 16 + li) * 136 + kc * 32 + lq * 8);
#pragma unroll
      for (int mt = 0; mt < 2; mt++)
#pragma unroll
        for (int nt = 0; nt < 4; nt++) acc2[mt][nt] = MFMA(a[mt], b[nt], acc2[mt][nt]);
    }
  }

  // ---- Epilogue: residual RMW, float4 per (mt,nt); 4-lane groups cover 64 B ----
#pragma unroll
  for (int mt = 0; mt < 2; mt++) {
    const int cb = c0 + mt * 16 + lq * 4;
    const float4 bb = *(const float4*)(fc2_b + layer * Cc + cb);
#pragma unroll
    for (int nt = 0; nt < 4; nt++) {
      const int tokn = nt * 16 + li;
      float* p = tok + (size_t)(t0 + tokn) * Cc + cb;
      const float4 g = *(const float4*)p;
      *(float4*)p = make_float4(g.x + acc2[mt][nt][0] + bb.x,
                                g.y + acc2[mt][nt][1] + bb.y,
                                g.z + acc2[mt][nt][2] + bb.z,
                                g.w + acc2[mt][nt][3] + bb.w);
    }
  }
}

// ---------------- head mean ----------------
__global__ __launch_bounds__(256) void head_kernel(const float* __restrict__ tok,
                                                   float* __restrict__ headbuf) {
  const int n = blockIdx.x >> 6, slice = blockIdx.x & 63;
  const int c = threadIdx.x & 127, half = threadIdx.x >> 7;
  const float* base = tok + ((size_t)n * HW + slice * 1200 + half * 600) * Cc + c;
  float s = 0.f;
  for (int i = 0; i < 600; i++) s += base[(size_t)i * Cc];
  atomicAdd(&headbuf[n * 128 + c], s * (1.f / 76800.f));
}

// ---------------- y head MLP ----------------
__global__ __launch_bounds__(256) void y_kernel(
    const float* __restrict__ headbuf,
    const float* __restrict__ r1_w, const float* __restrict__ r1_b,
    const float* __restrict__ r2_w, const float* __restrict__ r2_b,
    const float* __restrict__ r3_w, const float* __restrict__ r3_b,
    float* __restrict__ yout) {
  __shared__ float hb[128], y1[256], y2[256], red4[4];
  const int tid = threadIdx.x;
  const int n = blockIdx.x;
  if (tid < 128) hb[tid] = headbuf[n * 128 + tid];
  __syncthreads();
  {
    float s = r1_b[tid];
    const float* w = r1_w + (size_t)tid * 128;
    for (int c = 0; c < 128; c += 4) {
      const float4 w4 = *(const float4*)(w + c);
      s = fmaf(w4.x, hb[c], s); s = fmaf(w4.y, hb[c+1], s);
      s = fmaf(w4.z, hb[c+2], s); s = fmaf(w4.w, hb[c+3], s);
    }
    y1[tid] = s >= 0.f ? s : 0.01f * s;
  }
  __syncthreads();
  {
    float s = r2_b[tid];
    const float* w = r2_w + (size_t)tid * 256;
    for (int c = 0; c < 256; c += 4) {
      const float4 w4 = *(const float4*)(w + c);
      s = fmaf(w4.x, y1[c], s); s = fmaf(w4.y, y1[c+1], s);
      s = fmaf(w4.z, y1[c+2], s); s = fmaf(w4.w, y1[c+3], s);
    }
    y2[tid] = s >= 0.f ? s : 0.01f * s;
  }
  __syncthreads();
  float v;
  {
    float s = r3_b[tid];
    const float* w = r3_w + (size_t)tid * 256;
    for (int c = 0; c < 256; c += 4) {
      const float4 w4 = *(const float4*)(w + c);
      s = fmaf(w4.x, y2[c], s); s = fmaf(w4.y, y2[c+1], s);
      s = fmaf(w4.z, y2[c+2], s); s = fmaf(w4.w, y2[c+3], s);
    }
    v = (s > 0.f ? s : 0.f) + 0.1f;
  }
  float t = v;
#pragma unroll
  for (int m = 1; m < 64; m <<= 1) t += __shfl_xor(t, m);
  if ((tid & 63) == 0) red4[tid >> 6] = t;
  __syncthreads();
  const float tot = red4[0] + red4[1] + red4[2] + red4[3];
  yout[n * DOUT + tid] = v / tot;
}

// ---------------- maps prep: fold queries into conv weights ----------------
__global__ __launch_bounds__(256) void qprep_kernel(
    const float* __restrict__ tok, const float* __restrict__ conv_w, const float* __restrict__ conv_b,
    float* __restrict__ qwx, float* __restrict__ qb) {
  __shared__ float qs[16 * 128];  // [q_local][e]
  const int tid = threadIdx.x;
  const int n = blockIdx.x >> 3, g = blockIdx.x & 7;
  const int q0 = g * 16;
  for (int idx = tid; idx < 2048; idx += 256)
    qs[idx] = tok[((size_t)n * HW + q0 + (idx >> 7)) * Cc + (idx & 127)];
  __syncthreads();
  const int c = tid & 127, half = tid >> 7;
  float acc[8];
#pragma unroll
  for (int j = 0; j < 8; j++) acc[j] = 0.f;
  for (int e = 0; e < 128; e += 4) {
    const float w0 = conv_w[(e + 0) * 128 + c];
    const float w1 = conv_w[(e + 1) * 128 + c];
    const float w2 = conv_w[(e + 2) * 128 + c];
    const float w3 = conv_w[(e + 3) * 128 + c];
#pragma unroll
    for (int j = 0; j < 8; j++) {
      const float4 qv = *(const float4*)(qs + (half * 8 + j) * 128 + e);
      acc[j] = fmaf(qv.x, w0, fmaf(qv.y, w1, fmaf(qv.z, w2, fmaf(qv.w, w3, acc[j]))));
    }
  }
  float* dst = qwx + ((size_t)n * 128 + c) * 128 + q0 + half * 8;
#pragma unroll
  for (int j = 0; j < 8; j++) dst[j] = acc[j];
  if (tid < 16) {
    float s = 0.f;
    for (int e = 0; e < 128; e += 4) {
      const float4 qv = *(const float4*)(qs + tid * 128 + e);
      const float4 bv = *(const float4*)(conv_b + e);
      s = fmaf(qv.x, bv.x, fmaf(qv.y, bv.y, fmaf(qv.z, bv.z, fmaf(qv.w, bv.w, s))));
    }
    qb[n * 128 + q0 + tid] = s;
  }
}

// ---------------- maps v4: conv v5 structure (depth-4 prefetch, 16 KB chunks) ----------------
__global__ __launch_bounds__(256) void maps_kernel(
    const float* __restrict__ x, const float* __restrict__ qwx, const float* __restrict__ qb,
    float* __restrict__ mout) {
  __shared__ float qlds[32 * 128];  // [c-chunk][q], 16 KB
  const int tid = threadIdx.x;
  const int lane = tid & 63, w = tid >> 6;
  const int n = blockIdx.y;
  const int hw0 = blockIdx.x * 128;
  const int hwi = 2 * lane;
  const int q0 = 32 * w;
  const float* xn = x + (size_t)n * CIN * HW + hw0 + hwi;
  float acc[2][32];
#pragma unroll
  for (int jj = 0; jj < 8; jj++) {
    const float4 b4 = *(const float4*)(qb + n * 128 + q0 + jj * 4);
    acc[0][jj*4+0] = b4.x; acc[1][jj*4+0] = b4.x;
    acc[0][jj*4+1] = b4.y; acc[1][jj*4+1] = b4.y;
    acc[0][jj*4+2] = b4.z; acc[1][jj*4+2] = b4.z;
    acc[0][jj*4+3] = b4.w; acc[1][jj*4+3] = b4.w;
  }
  float2 xv[4];
#pragma unroll
  for (int j = 0; j < 4; j++) xv[j] = *(const float2*)(xn + (size_t)j * HW);
  for (int ch = 0; ch < 4; ch++) {
    if (ch) __syncthreads();
    for (int idx = tid * 4; idx < 4096; idx += 1024)
      *(float4*)(qlds + idx) = *(const float4*)(qwx + (size_t)n * 16384 + ch * 4096 + idx);
    __syncthreads();
    for (int cg = 0; cg < 32; cg += 4) {
      float2 nx[4];
#pragma unroll
      for (int j = 0; j < 4; j++) {
        int cn = ch * 32 + cg + 4 + j;
        if (cn > 127) cn = 127;
        nx[j] = *(const float2*)(xn + (size_t)cn * HW);
      }
#pragma unroll
      for (int j = 0; j < 4; j++) {
        const float* ql = qlds + (cg + j) * 128 + q0;
#pragma unroll
        for (int jj = 0; jj < 8; jj++) {
          const float4 w4 = *(const float4*)(ql + jj * 4);
          acc[0][jj*4+0] = fmaf(w4.x, xv[j].x, acc[0][jj*4+0]); acc[1][jj*4+0] = fmaf(w4.x, xv[j].y, acc[1][jj*4+0]);
          acc[0][jj*4+1] = fmaf(w4.y, xv[j].x, acc[0][jj*4+1]); acc[1][jj*4+1] = fmaf(w4.y, xv[j].y, acc[1][jj*4+1]);
          acc[0][jj*4+2] = fmaf(w4.z, xv[j].x, acc[0][jj*4+2]); acc[1][jj*4+2] = fmaf(w4.z, xv[j].y, acc[1][jj*4+2]);
          acc[0][jj*4+3] = fmaf(w4.w, xv[j].x, acc[0][jj*4+3]); acc[1][jj*4+3] = fmaf(w4.w, xv[j].y, acc[1][jj*4+3]);
        }
      }
#pragma unroll
      for (int j = 0; j < 4; j++) xv[j] = nx[j];
    }
  }
  float* mb = mout + ((size_t)n * 128 + q0) * HW + hw0 + hwi;
#pragma unroll
  for (int jj = 0; jj < 32; jj++) {
    *(float2*)(mb + (size_t)jj * HW) = make_float2(acc[0][jj], acc[1][jj]);
  }
}

extern "C" void kernel_launch(void* const* d_in, const int* in_sizes, int n_in,
                              void* d_out, int out_size, void* d_ws, size_t ws_size,
                              hipStream_t stream) {
  const float* x      = (const float*)d_in[0];
  const float* conv_w = (const float*)d_in[1];
  const float* conv_b = (const float*)d_in[2];
  const float* n1_g   = (const float*)d_in[3];
  const float* n1_b   = (const float*)d_in[4];
  const float* qkv_w  = (const float*)d_in[5];
  const float* qkv_b  = (const float*)d_in[6];
  const float* proj_w = (const float*)d_in[7];
  const float* proj_b = (const float*)d_in[8];
  const float* n2_g   = (const float*)d_in[9];
  const float* n2_b   = (const float*)d_in[10];
  const float* fc1_w  = (const float*)d_in[11];
  const float* fc1_b  = (const float*)d_in[12];
  const float* fc2_w  = (const float*)d_in[13];
  const float* fc2_b  = (const float*)d_in[14];
  const float* r1_w   = (const float*)d_in[15];
  const float* r1_b   = (const float*)d_in[16];
  const float* r2_w   = (const float*)d_in[17];
  const float* r2_b   = (const float*)d_in[18];
  const float* r3_w   = (const float*)d_in[19];
  const float* r3_b   = (const float*)d_in[20];

  // Token residual stream (f32) lives in the d_out maps region; consumed before maps.
  float* out = (float*)d_out;
  float* tok = out + 512;

  // ws: bf16 weight copies (1.57 MB) + qwx/qb/headbuf
  char* ws = (char*)d_ws;
  short* wqkv = (short*)ws;                       // 4*384*128
  short* wproj = (short*)(ws + 393216);           // 4*128*128
  short* wfc1 = (short*)(ws + 524288);            // 4*512*128
  short* wfc2 = (short*)(ws + 1048576);           // 4*128*512
  float* qwx = (float*)(ws + 1572864);            // 2*128*128 f32
  float* qb = (float*)(ws + 1703936);             // 2*128
  float* headbuf = (float*)(ws + 1704960);        // 2*128
  // wconvT aliases the qwx region: used only by conv (early); qwx written by
  // qprep (late). 128*128 f32 = 64 KB <= qwx's 128 KB.
  float* wconvT = qwx;

  cast_bf16<<<196608 / 1024, 256, 0, stream>>>(qkv_w, wqkv, 196608);
  cast_bf16<<<65536 / 1024, 256, 0, stream>>>(proj_w, wproj, 65536);
  cast_bf16<<<262144 / 1024, 256, 0, stream>>>(fc1_w, wfc1, 262144);
  cast_bf16<<<262144 / 1024, 256, 0, stream>>>(fc2_w, wfc2, 262144);
  init_head<<<1, 256, 0, stream>>>(headbuf);
  transp_w<<<64, 256, 0, stream>>>(conv_w, wconvT);
  conv_kernel<<<dim3(600, 2), 256, 0, stream>>>(x, wconvT, conv_b, tok);
  for (int l = 0; l < 4; l++) {
    attn_kernel<<<NWIN, 256, 0, stream>>>(tok, n1_g, n1_b, wqkv, qkv_b, wproj, proj_b, l);
    mlp_kernel<<<2400, 256, 0, stream>>>(tok, n2_g, n2_b, wfc1, fc1_b, wfc2, fc2_b, l);
  }
  head_kernel<<<128, 256, 0, stream>>>(tok, headbuf);
  y_kernel<<<2, 256, 0, stream>>>(headbuf, r1_w, r1_b, r2_w, r2_b, r3_w, r3_b, out);
  qprep_kernel<<<16, 256, 0, stream>>>(tok, conv_w, conv_b, qwx, qb);
  maps_kernel<<<dim3(600, 2), 256, 0, stream>>>(x, qwx, qb, out + 512);
}

// Round 12
// 1328.838 us; speedup vs baseline: 1.0632x; 1.0059x over previous
//
#include <hip/hip_runtime.h>
#include <hip/hip_bf16.h>

typedef __hip_bfloat16 bf16;

// Problem constants
static constexpr int Nn = 2, CIN = 128, Hh = 240, Ww = 320, HW = 76800;
static constexpr int Cc = 128, HID = 512, DOUT = 256, WSQ = 49;
static constexpr int NWH = 35, NWW = 46, WPN = NWH * NWW;   // 1610 windows per image
static constexpr int NWIN = Nn * WPN;                        // 3220
static constexpr float SCALE = 0.17677669529663687f;         // 32^-0.5

// attn LDS geometry (v3): 4 head slices + xw/vT region = 25,856 shorts = 51,712 B
static constexpr int SLICE = 4160;   // shorts per head slice (q[52][40], k @2080)
static constexpr int KOFF  = 2080;
static constexpr int TRIM  = 52;     // q/k rows stored; >=49 masked downstream
static constexpr int XWOFF = 16640;  // 4*SLICE

typedef __attribute__((ext_vector_type(8))) short s8;   // 8 bf16 = one MFMA A/B frag
typedef __attribute__((ext_vector_type(4))) short s4;   // packed 4-bf16 LDS write
typedef __attribute__((ext_vector_type(2))) short s2;
typedef __attribute__((ext_vector_type(4))) float f4;   // MFMA accumulator

__device__ __forceinline__ short f2bf(float x) {
  union { bf16 b; short s; } u; u.b = __float2bfloat16(x); return u.s;
}

// tanh-form gelu via HW exp (numerics validated R8-R11, neutral perf vs erff).
__device__ __forceinline__ float gelu_f(float x) {
  const float u = 0.7978845608028654f * fmaf(0.044715f * x, x * x, x);
  const float e = __expf(2.f * u);
  const float t = fmaf(-2.f, __frcp_rn(e + 1.f), 1.f);   // tanh(u)
  return 0.5f * x * (1.f + t);
}

#define MFMA(a, b, c) __builtin_amdgcn_mfma_f32_16x16x32_bf16((a), (b), (c), 0, 0, 0)

// ---------------- weight cast: f32 -> bf16 (once per launch) ----------------
__global__ __launch_bounds__(256) void cast_bf16(const float* __restrict__ src,
                                                 short* __restrict__ dst, int n) {
  const int i = (blockIdx.x * 256 + threadIdx.x) * 4;
  if (i < n) {
    const float4 v = *(const float4*)(src + i);
    s4 o; o[0] = f2bf(v.x); o[1] = f2bf(v.y); o[2] = f2bf(v.z); o[3] = f2bf(v.w);
    *(s4*)(dst + i) = o;
  }
}

__global__ void init_head(float* headbuf) {
  if (threadIdx.x < 256) headbuf[threadIdx.x] = 0.f;
}

// ---------------- conv_w transpose: wT[c][e] = conv_w[e][c] (once) ----------------
__global__ __launch_bounds__(256) void transp_w(const float* __restrict__ conv_w,
                                                float* __restrict__ wT) {
  const int idx = blockIdx.x * 256 + threadIdx.x;   // 16384 total
  const int c = idx >> 7, e = idx & 127;
  wT[c * 128 + e] = conv_w[e * 128 + c];
}

// ---------------- 1x1 conv -> residual stream tok[n,hw,e] (f32, in d_out) ----------------
// v5: depth-4 x-prefetch + 16 KB LDS chunks. No forced min-occupancy.
__global__ __launch_bounds__(256) void conv_kernel(
    const float* __restrict__ x, const float* __restrict__ wT, const float* __restrict__ conv_b,
    float* __restrict__ tok) {
  __shared__ float wlds[32 * 128];  // [c-chunk][e], 16 KB
  const int tid = threadIdx.x;
  const int lane = tid & 63, w = tid >> 6;
  const int n = blockIdx.y;
  const int hw0 = blockIdx.x * 128;
  const int hwi = 2 * lane;         // thread owns hw pair (hwi, hwi+1)
  const int e0 = 32 * w;            // wave owns 32-wide e slice
  const float* xn = x + (size_t)n * CIN * HW + hw0 + hwi;
  float acc[2][32];
#pragma unroll
  for (int jj = 0; jj < 8; jj++) {
    const float4 b4 = *(const float4*)(conv_b + e0 + jj * 4);
    acc[0][jj*4+0] = b4.x; acc[1][jj*4+0] = b4.x;
    acc[0][jj*4+1] = b4.y; acc[1][jj*4+1] = b4.y;
    acc[0][jj*4+2] = b4.z; acc[1][jj*4+2] = b4.z;
    acc[0][jj*4+3] = b4.w; acc[1][jj*4+3] = b4.w;
  }
  float2 xv[4];
#pragma unroll
  for (int j = 0; j < 4; j++) xv[j] = *(const float2*)(xn + (size_t)j * HW);
  for (int ch = 0; ch < 4; ch++) {
    if (ch) __syncthreads();        // all waves done reading previous chunk
    for (int idx = tid * 4; idx < 4096; idx += 1024)
      *(float4*)(wlds + idx) = *(const float4*)(wT + ch * 4096 + idx);
    __syncthreads();
    for (int cg = 0; cg < 32; cg += 4) {
      float2 nx[4];
#pragma unroll
      for (int j = 0; j < 4; j++) {
        int cn = ch * 32 + cg + 4 + j;          // prefetch next group (may cross chunk)
        if (cn > 127) cn = 127;                 // tail clamp: dummy valid load
        nx[j] = *(const float2*)(xn + (size_t)cn * HW);
      }
#pragma unroll
      for (int j = 0; j < 4; j++) {
        const float* wl = wlds + (cg + j) * 128 + e0;
#pragma unroll
        for (int jj = 0; jj < 8; jj++) {
          const float4 w4 = *(const float4*)(wl + jj * 4);
          acc[0][jj*4+0] = fmaf(w4.x, xv[j].x, acc[0][jj*4+0]); acc[1][jj*4+0] = fmaf(w4.x, xv[j].y, acc[1][jj*4+0]);
          acc[0][jj*4+1] = fmaf(w4.y, xv[j].x, acc[0][jj*4+1]); acc[1][jj*4+1] = fmaf(w4.y, xv[j].y, acc[1][jj*4+1]);
          acc[0][jj*4+2] = fmaf(w4.z, xv[j].x, acc[0][jj*4+2]); acc[1][jj*4+2] = fmaf(w4.z, xv[j].y, acc[1][jj*4+2]);
          acc[0][jj*4+3] = fmaf(w4.w, xv[j].x, acc[0][jj*4+3]); acc[1][jj*4+3] = fmaf(w4.w, xv[j].y, acc[1][jj*4+3]);
        }
      }
#pragma unroll
      for (int j = 0; j < 4; j++) xv[j] = nx[j];
    }
  }
  float* tb0 = tok + ((size_t)n * HW + hw0 + hwi) * Cc + e0;
  float* tb1 = tb0 + Cc;
#pragma unroll
  for (int jj = 0; jj < 8; jj++) {
    *(float4*)(tb0 + jj * 4) = make_float4(acc[0][jj*4], acc[0][jj*4+1], acc[0][jj*4+2], acc[0][jj*4+3]);
    *(float4*)(tb1 + jj * 4) = make_float4(acc[1][jj*4], acc[1][jj*4+1], acc[1][jj*4+2], acc[1][jj*4+3]);
  }
}

// ---------------- fused window attention v3 (see R6 notes) ----------------
__global__ __launch_bounds__(256, 2) void attn_kernel(
    float* __restrict__ tok,
    const float* __restrict__ n1_g, const float* __restrict__ n1_b,
    const short* __restrict__ wqkv, const float* __restrict__ qkv_b,
    const short* __restrict__ wproj, const float* __restrict__ proj_b,
    int layer) {
  __shared__ __align__(16) short ms[25856];
  short* xwv = ms + XWOFF;

  const int tid = threadIdx.x;
  const int w = tid >> 6, lane = tid & 63;
  const int lq = lane >> 4, li = lane & 15;
  const int wi = blockIdx.x;
  const int n = wi / WPN;
  const int r0 = wi % WPN;
  const int wh = r0 / NWW, ww = r0 % NWW;

  const short* wqkv_l = wqkv + (size_t)layer * 384 * 128;
  const short* wproj_l = wproj + (size_t)layer * 128 * 128;

  // ---- Phase 1a: coalesced gather -> g32 f32 [49][128] (slice region) ----
  {
    float* g32 = (float*)ms;
    for (int idx = tid; idx < WSQ * 32; idx += 256) {
      const int t = idx >> 5, c4 = (idx & 31) * 4;
      const int hh = wh * 7 + t / 7, wv = ww * 7 + t % 7;
      float4 v = make_float4(0.f, 0.f, 0.f, 0.f);
      if (hh < Hh && wv < Ww)
        v = *(const float4*)(tok + ((size_t)n * HW + hh * Ww + wv) * Cc + c4);
      *(float4*)(g32 + t * 128 + c4) = v;
    }
    for (int idx = tid; idx < 15 * 136; idx += 256)
      xwv[(49 + idx / 136) * 136 + (idx % 136)] = 0;
    __syncthreads();
    // ---- Phase 1b: LayerNorm from LDS -> xw bf16 [64][136] ----
    for (int ti = w; ti < WSQ; ti += 4) {
      const int hh = wh * 7 + ti / 7, wv = ww * 7 + ti % 7;
      const bool valid = (hh < Hh) && (wv < Ww);
      const float2 v = *(const float2*)(g32 + ti * 128 + 2 * lane);
      float s = v.x + v.y, q = v.x * v.x + v.y * v.y;
#pragma unroll
      for (int m = 1; m < 64; m <<= 1) { s += __shfl_xor(s, m); q += __shfl_xor(q, m); }
      const float mean = s * (1.f / 128.f);
      const float rstd = rsqrtf(fmaxf(q * (1.f / 128.f) - mean * mean, 0.f) + 1e-5f);
      const int c = 2 * lane;
      float o0 = 0.f, o1 = 0.f;
      if (valid) {
        o0 = (v.x - mean) * rstd * n1_g[layer * Cc + c]     + n1_b[layer * Cc + c];
        o1 = (v.y - mean) * rstd * n1_g[layer * Cc + c + 1] + n1_b[layer * Cc + c + 1];
      }
      s2 pk; pk[0] = f2bf(o0); pk[1] = f2bf(o1);
      *(s2*)(xwv + ti * 136 + c) = pk;
    }
  }
  __syncthreads();   // g32 consumed; slices may now be overwritten by q/k

  // ---- Phase 2a: q,k transposed: D'[n][token] = wqkv . xw^T ----
  {
    const int n0 = 64 * w;
    f4 acc[4][4];
#pragma unroll
    for (int mt = 0; mt < 4; mt++)
#pragma unroll
      for (int nt = 0; nt < 4; nt++) acc[mt][nt] = f4{0.f, 0.f, 0.f, 0.f};
    for (int s = 0; s < 4; s++) {
      s8 a[4], b[4];
#pragma unroll
      for (int mt = 0; mt < 4; mt++)
        a[mt] = *(const s8*)(wqkv_l + (n0 + mt * 16 + li) * 128 + s * 32 + lq * 8);
#pragma unroll
      for (int nt = 0; nt < 4; nt++)
        b[nt] = *(const s8*)(xwv + (nt * 16 + li) * 136 + s * 32 + lq * 8);
#pragma unroll
      for (int mt = 0; mt < 4; mt++)
#pragma unroll
        for (int nt = 0; nt < 4; nt++) acc[mt][nt] = MFMA(a[mt], b[nt], acc[mt][nt]);
    }
    const bool isq = (w < 2);
    const float scl = isq ? SCALE : 1.f;
    const int koff = isq ? 0 : KOFF;
#pragma unroll
    for (int mt = 0; mt < 4; mt++) {
      const int nbase = n0 + mt * 16 + lq * 4;            // qkv output row (r=0)
      const int hsel = (isq ? nbase : (nbase - 128)) >> 5;
      const int d0 = nbase & 31;
      const float4 bb = *(const float4*)(qkv_b + layer * 384 + nbase);
#pragma unroll
      for (int nt = 0; nt < 4; nt++) {
        const int tokn = nt * 16 + li;
        if (tokn < TRIM) {   // rows >= TRIM trimmed (masked downstream)
          s4 pk;
          pk[0] = f2bf((acc[mt][nt][0] + bb.x) * scl);
          pk[1] = f2bf((acc[mt][nt][1] + bb.y) * scl);
          pk[2] = f2bf((acc[mt][nt][2] + bb.z) * scl);
          pk[3] = f2bf((acc[mt][nt][3] + bb.w) * scl);
          *(s4*)(ms + hsel * SLICE + koff + tokn * 40 + d0) = pk;
        }
      }
    }
  }

  // ---- Phase 2b: v straight: D[token][n] = xw . wqkv_v^T ; export vT[d][token] ----
  {
    const int n0v = 32 * w;
    f4 acc2[4][2];
#pragma unroll
    for (int mt = 0; mt < 4; mt++)
#pragma unroll
      for (int nt = 0; nt < 2; nt++) acc2[mt][nt] = f4{0.f, 0.f, 0.f, 0.f};
    for (int s = 0; s < 4; s++) {
      s8 a[4], b[2];
#pragma unroll
      for (int mt = 0; mt < 4; mt++)
        a[mt] = *(const s8*)(xwv + (mt * 16 + li) * 136 + s * 32 + lq * 8);
#pragma unroll
      for (int nt = 0; nt < 2; nt++)
        b[nt] = *(const s8*)(wqkv_l + (256 + n0v + nt * 16 + li) * 128 + s * 32 + lq * 8);
#pragma unroll
      for (int mt = 0; mt < 4; mt++)
#pragma unroll
        for (int nt = 0; nt < 2; nt++) acc2[mt][nt] = MFMA(a[mt], b[nt], acc2[mt][nt]);
    }
    __syncthreads();  // all xw reads + all q/k writes complete
#pragma unroll
    for (int nt = 0; nt < 2; nt++) {
      const int d = n0v + nt * 16 + li;
      const float bv = qkv_b[layer * 384 + 256 + d];
#pragma unroll
      for (int mt = 0; mt < 4; mt++) {
        const int m0 = mt * 16 + lq * 4;
        s4 pk;
        pk[0] = f2bf(acc2[mt][nt][0] + bv);
        pk[1] = f2bf(acc2[mt][nt][1] + bv);
        pk[2] = f2bf(acc2[mt][nt][2] + bv);
        pk[3] = f2bf(acc2[mt][nt][3] + bv);
        *(s4*)(xwv + d * 72 + m0) = pk;
      }
    }
  }

  // ---- Phase 3: per-head (wave = head): S^T = K.Q^T -> softmax -> O^T = V^T.P^T ----
  {
    short* qbase = ms + w * SLICE;
    short* kbase = qbase + KOFF;
    s8 ak[4], bq[4];
#pragma unroll
    for (int kt = 0; kt < 4; kt++) ak[kt] = *(const s8*)(kbase + (kt * 16 + li) * 40 + lq * 8);
#pragma unroll
    for (int qt = 0; qt < 4; qt++) bq[qt] = *(const s8*)(qbase + (qt * 16 + li) * 40 + lq * 8);
    f4 sc[4][4];
#pragma unroll
    for (int kt = 0; kt < 4; kt++)
#pragma unroll
      for (int qt = 0; qt < 4; qt++) sc[kt][qt] = f4{0.f, 0.f, 0.f, 0.f};
#pragma unroll
    for (int kt = 0; kt < 4; kt++)
#pragma unroll
      for (int qt = 0; qt < 4; qt++) sc[kt][qt] = MFMA(ak[kt], bq[qt], sc[kt][qt]);
#pragma unroll
    for (int kt = 0; kt < 4; kt++)
#pragma unroll
      for (int r = 0; r < 4; r++)
        if (kt * 16 + lq * 4 + r >= WSQ) {
#pragma unroll
          for (int qt = 0; qt < 4; qt++) sc[kt][qt][r] = -1e30f;
        }
    float inv[4];
#pragma unroll
    for (int qt = 0; qt < 4; qt++) {
      float m = -1e30f;
#pragma unroll
      for (int kt = 0; kt < 4; kt++)
#pragma unroll
        for (int r = 0; r < 4; r++) m = fmaxf(m, sc[kt][qt][r]);
      m = fmaxf(m, __shfl_xor(m, 16));
      m = fmaxf(m, __shfl_xor(m, 32));
      float ssum = 0.f;
#pragma unroll
      for (int kt = 0; kt < 4; kt++)
#pragma unroll
        for (int r = 0; r < 4; r++) {
          const float e = __expf(sc[kt][qt][r] - m);
          sc[kt][qt][r] = e; ssum += e;
        }
      ssum += __shfl_xor(ssum, 16);
      ssum += __shfl_xor(ssum, 32);
      inv[qt] = 1.f / ssum;
    }
#pragma unroll
    for (int qt = 0; qt < 4; qt++) {
      const int qq = qt * 16 + li;
      if (qq < TRIM) {
#pragma unroll
        for (int kt = 0; kt < 4; kt++) {
          s4 pk;
          pk[0] = f2bf(sc[kt][qt][0] * inv[qt]);
          pk[1] = f2bf(sc[kt][qt][1] * inv[qt]);
          pk[2] = f2bf(sc[kt][qt][2] * inv[qt]);
          pk[3] = f2bf(sc[kt][qt][3] * inv[qt]);
          *(s4*)(qbase + qq * 72 + kt * 16 + lq * 4) = pk;
        }
      }
    }
    f4 ov[2][4];
#pragma unroll
    for (int dt = 0; dt < 2; dt++)
#pragma unroll
      for (int qt = 0; qt < 4; qt++) ov[dt][qt] = f4{0.f, 0.f, 0.f, 0.f};
    for (int s = 0; s < 2; s++) {
      s8 av[2], bp[4];
#pragma unroll
      for (int dt = 0; dt < 2; dt++)
        av[dt] = *(const s8*)(xwv + (w * 32 + dt * 16 + li) * 72 + s * 32 + lq * 8);
#pragma unroll
      for (int qt = 0; qt < 4; qt++)
        bp[qt] = *(const s8*)(qbase + (qt * 16 + li) * 72 + s * 32 + lq * 8);
#pragma unroll
      for (int dt = 0; dt < 2; dt++)
#pragma unroll
        for (int qt = 0; qt < 4; qt++) ov[dt][qt] = MFMA(av[dt], bp[qt], ov[dt][qt]);
    }
    short* ohb = qbase;
#pragma unroll
    for (int dt = 0; dt < 2; dt++) {
      const int dl0 = dt * 16 + lq * 4;
#pragma unroll
      for (int qt = 0; qt < 4; qt++) {
        const int tokn = qt * 16 + li;
        s4 pk;
        pk[0] = f2bf(ov[dt][qt][0]);
        pk[1] = f2bf(ov[dt][qt][1]);
        pk[2] = f2bf(ov[dt][qt][2]);
        pk[3] = f2bf(ov[dt][qt][3]);
        *(s4*)(ohb + tokn * 40 + dl0) = pk;
      }
    }
  }
  __syncthreads();

  // ---- Phase 4: proj straight: D[token][c] = o . wproj^T ; staged residual RMW ----
  {
    const int n0p = 32 * w;
    f4 pa[4][2];
#pragma unroll
    for (int mt = 0; mt < 4; mt++)
#pragma unroll
      for (int nt = 0; nt < 2; nt++) pa[mt][nt] = f4{0.f, 0.f, 0.f, 0.f};
    for (int s = 0; s < 4; s++) {
      s8 ao[4], bw[2];
#pragma unroll
      for (int mt = 0; mt < 4; mt++)
        ao[mt] = *(const s8*)(ms + s * SLICE + (mt * 16 + li) * 40 + lq * 8);
#pragma unroll
      for (int nt = 0; nt < 2; nt++)
        bw[nt] = *(const s8*)(wproj_l + (n0p + nt * 16 + li) * 128 + s * 32 + lq * 8);
#pragma unroll
      for (int mt = 0; mt < 4; mt++)
#pragma unroll
        for (int nt = 0; nt < 2; nt++) pa[mt][nt] = MFMA(ao[mt], bw[nt], pa[mt][nt]);
    }
    __syncthreads();  // all o reads done everywhere; ms fully dead -> res
    float* res = (float*)ms;   // [64][132] f32 = 33,792 B
#pragma unroll
    for (int nt = 0; nt < 2; nt++) {
      const int c = n0p + nt * 16 + li;
#pragma unroll
      for (int mt = 0; mt < 4; mt++) {
#pragma unroll
        for (int r = 0; r < 4; r++) {
          const int m = mt * 16 + lq * 4 + r;
          res[m * 132 + c] = pa[mt][nt][r];
        }
      }
    }
    __syncthreads();
    for (int idx = tid; idx < WSQ * 32; idx += 256) {
      const int t = idx >> 5, c4 = (idx & 31) * 4;
      const int hh = wh * 7 + t / 7, wv = ww * 7 + t % 7;
      if (hh < Hh && wv < Ww) {
        float* p = tok + ((size_t)n * HW + hh * Ww + wv) * Cc + c4;
        const float4 g = *(const float4*)p;
        const float4 r4 = *(const float4*)(res + t * 132 + c4);
        const float4 pb4 = *(const float4*)(proj_b + layer * 128 + c4);
        *(float4*)p = make_float4(g.x + r4.x + pb4.x, g.y + r4.y + pb4.y,
                                  g.z + r4.z + pb4.z, g.w + r4.w + pb4.w);
      }
    }
  }
}

// ---------------- fused MLP v7: 512 threads (8 waves), 64 tok/block ----------------
// v2-v6 all pinned at ~144 us: LDS/tile occupancy levers dead (2 blocks/CU
// whatever the footprint), per-block lifetime ~30 us = issue (2.2 waves/SIMD)
// + latency. The untried occupancy lever is THREADS PER BLOCK: 512 threads
// keeps LDS identical (52,224 B, 2 blocks/CU) but doubles resident waves/CU
// (9 -> 16, 4/SIMD). Each wave owns 16 rows (fc1 h, fc2 c) instead of 32:
// per-wave MFMA 256 -> 128, gelu halves, registers shrink. Same dbuf + 5
// barriers. Single-variable change vs R11.
__global__ __launch_bounds__(512) void mlp_kernel(
    float* __restrict__ tok,
    const float* __restrict__ n2_g, const float* __restrict__ n2_b,
    const short* __restrict__ wfc1, const float* __restrict__ fc1_b,
    const short* __restrict__ wfc2, const float* __restrict__ fc2_b,
    int layer) {
  __shared__ __align__(16) short lnb[64 * 136];      // LN'd tokens bf16 [64][136]
  __shared__ __align__(16) short hbuf[2][64 * 136];  // hid slice bf16 [tok][128] (dbuf)

  const int tid = threadIdx.x;
  const int w = tid >> 6, lane = tid & 63;           // w in [0,8)
  const int lq = lane >> 4, li = lane & 15;
  const int t0 = blockIdx.x * 64;
  const short* wfc1_l = wfc1 + (size_t)layer * 512 * 128;
  const short* wfc2_l = wfc2 + (size_t)layer * 128 * 512;

  // ---- Phase 1: LN -> lnb bf16 (wave w owns tokens [8w, 8w+8)) ----
#pragma unroll
  for (int i = 0; i < 8; i++) {
    const int tl = w * 8 + i;
    const float2 v = *(const float2*)(tok + (size_t)(t0 + tl) * Cc + 2 * lane);
    float s = v.x + v.y, q = v.x * v.x + v.y * v.y;
#pragma unroll
    for (int m = 1; m < 64; m <<= 1) { s += __shfl_xor(s, m); q += __shfl_xor(q, m); }
    const float mean = s * (1.f / 128.f);
    const float rstd = rsqrtf(fmaxf(q * (1.f / 128.f) - mean * mean, 0.f) + 1e-5f);
    const int c = 2 * lane;
    s2 pk;
    pk[0] = f2bf((v.x - mean) * rstd * n2_g[layer * Cc + c]     + n2_b[layer * Cc + c]);
    pk[1] = f2bf((v.y - mean) * rstd * n2_g[layer * Cc + c + 1] + n2_b[layer * Cc + c + 1]);
    *(s2*)(lnb + tl * 136 + c) = pk;
  }
  __syncthreads();

  // fc2 output accumulators: wave w owns c-rows [16w, 16w+16), all 64 tokens.
  f4 acc2[4];
#pragma unroll
  for (int nt = 0; nt < 4; nt++) acc2[nt] = f4{0.f, 0.f, 0.f, 0.f};
  const int c0 = 16 * w;

  // ---- Rounds: fc1 h-slice [128s,128s+128) -> gelu -> hbuf -> fc2 partial ----
  for (int s = 0; s < 4; s++) {
    f4 acc1[4];
#pragma unroll
    for (int nt = 0; nt < 4; nt++) acc1[nt] = f4{0.f, 0.f, 0.f, 0.f};
    const int hbase = 128 * s + 16 * w;   // wave w's 16 h-rows this round
    for (int kc = 0; kc < 4; kc++) {
      const s8 a = *(const s8*)(wfc1_l + (hbase + li) * 128 + kc * 32 + lq * 8);
      s8 b[4];
#pragma unroll
      for (int nt = 0; nt < 4; nt++)
        b[nt] = *(const s8*)(lnb + (nt * 16 + li) * 136 + kc * 32 + lq * 8);
#pragma unroll
      for (int nt = 0; nt < 4; nt++) acc1[nt] = MFMA(a, b[nt], acc1[nt]);
    }
    short* hb = hbuf[s & 1];
    {
      const int hl0 = 16 * w + lq * 4;                 // h_local in [0,128)
      const float4 bb = *(const float4*)(fc1_b + layer * HID + 128 * s + hl0);
#pragma unroll
      for (int nt = 0; nt < 4; nt++) {
        const int tokn = nt * 16 + li;
        s4 pk;
        pk[0] = f2bf(gelu_f(acc1[nt][0] + bb.x));
        pk[1] = f2bf(gelu_f(acc1[nt][1] + bb.y));
        pk[2] = f2bf(gelu_f(acc1[nt][2] + bb.z));
        pk[3] = f2bf(gelu_f(acc1[nt][3] + bb.w));
        *(s4*)(hb + tokn * 136 + hl0) = pk;
      }
    }
    __syncthreads();  // hbuf[s&1] complete; safe vs round s+2 by barrier s+1
    for (int kc = 0; kc < 4; kc++) {
      const s8 a = *(const s8*)(wfc2_l + (c0 + li) * 512 + s * 128 + kc * 32 + lq * 8);
      s8 b[4];
#pragma unroll
      for (int nt = 0; nt < 4; nt++)
        b[nt] = *(const s8*)(hb + (nt * 16 + li) * 136 + kc * 32 + lq * 8);
#pragma unroll
      for (int nt = 0; nt < 4; nt++) acc2[nt] = MFMA(a, b[nt], acc2[nt]);
    }
  }

  // ---- Epilogue: residual RMW, float4 per nt; wave w covers c [16w,16w+16) ----
  {
    const int cb = c0 + lq * 4;
    const float4 bb = *(const float4*)(fc2_b + layer * Cc + cb);
#pragma unroll
    for (int nt = 0; nt < 4; nt++) {
      const int tokn = nt * 16 + li;
      float* p = tok + (size_t)(t0 + tokn) * Cc + cb;
      const float4 g = *(const float4*)p;
      *(float4*)p = make_float4(g.x + acc2[nt][0] + bb.x,
                                g.y + acc2[nt][1] + bb.y,
                                g.z + acc2[nt][2] + bb.z,
                                g.w + acc2[nt][3] + bb.w);
    }
  }
}

// ---------------- head mean ----------------
__global__ __launch_bounds__(256) void head_kernel(const float* __restrict__ tok,
                                                   float* __restrict__ headbuf) {
  const int n = blockIdx.x >> 6, slice = blockIdx.x & 63;
  const int c = threadIdx.x & 127, half = threadIdx.x >> 7;
  const float* base = tok + ((size_t)n * HW + slice * 1200 + half * 600) * Cc + c;
  float s = 0.f;
  for (int i = 0; i < 600; i++) s += base[(size_t)i * Cc];
  atomicAdd(&headbuf[n * 128 + c], s * (1.f / 76800.f));
}

// ---------------- y head MLP ----------------
__global__ __launch_bounds__(256) void y_kernel(
    const float* __restrict__ headbuf,
    const float* __restrict__ r1_w, const float* __restrict__ r1_b,
    const float* __restrict__ r2_w, const float* __restrict__ r2_b,
    const float* __restrict__ r3_w, const float* __restrict__ r3_b,
    float* __restrict__ yout) {
  __shared__ float hb[128], y1[256], y2[256], red4[4];
  const int tid = threadIdx.x;
  const int n = blockIdx.x;
  if (tid < 128) hb[tid] = headbuf[n * 128 + tid];
  __syncthreads();
  {
    float s = r1_b[tid];
    const float* w = r1_w + (size_t)tid * 128;
    for (int c = 0; c < 128; c += 4) {
      const float4 w4 = *(const float4*)(w + c);
      s = fmaf(w4.x, hb[c], s); s = fmaf(w4.y, hb[c+1], s);
      s = fmaf(w4.z, hb[c+2], s); s = fmaf(w4.w, hb[c+3], s);
    }
    y1[tid] = s >= 0.f ? s : 0.01f * s;
  }
  __syncthreads();
  {
    float s = r2_b[tid];
    const float* w = r2_w + (size_t)tid * 256;
    for (int c = 0; c < 256; c += 4) {
      const float4 w4 = *(const float4*)(w + c);
      s = fmaf(w4.x, y1[c], s); s = fmaf(w4.y, y1[c+1], s);
      s = fmaf(w4.z, y1[c+2], s); s = fmaf(w4.w, y1[c+3], s);
    }
    y2[tid] = s >= 0.f ? s : 0.01f * s;
  }
  __syncthreads();
  float v;
  {
    float s = r3_b[tid];
    const float* w = r3_w + (size_t)tid * 256;
    for (int c = 0; c < 256; c += 4) {
      const float4 w4 = *(const float4*)(w + c);
      s = fmaf(w4.x, y2[c], s); s = fmaf(w4.y, y2[c+1], s);
      s = fmaf(w4.z, y2[c+2], s); s = fmaf(w4.w, y2[c+3], s);
    }
    v = (s > 0.f ? s : 0.f) + 0.1f;
  }
  float t = v;
#pragma unroll
  for (int m = 1; m < 64; m <<= 1) t += __shfl_xor(t, m);
  if ((tid & 63) == 0) red4[tid >> 6] = t;
  __syncthreads();
  const float tot = red4[0] + red4[1] + red4[2] + red4[3];
  yout[n * DOUT + tid] = v / tot;
}

// ---------------- maps prep: fold queries into conv weights ----------------
__global__ __launch_bounds__(256) void qprep_kernel(
    const float* __restrict__ tok, const float* __restrict__ conv_w, const float* __restrict__ conv_b,
    float* __restrict__ qwx, float* __restrict__ qb) {
  __shared__ float qs[16 * 128];  // [q_local][e]
  const int tid = threadIdx.x;
  const int n = blockIdx.x >> 3, g = blockIdx.x & 7;
  const int q0 = g * 16;
  for (int idx = tid; idx < 2048; idx += 256)
    qs[idx] = tok[((size_t)n * HW + q0 + (idx >> 7)) * Cc + (idx & 127)];
  __syncthreads();
  const int c = tid & 127, half = tid >> 7;
  float acc[8];
#pragma unroll
  for (int j = 0; j < 8; j++) acc[j] = 0.f;
  for (int e = 0; e < 128; e += 4) {
    const float w0 = conv_w[(e + 0) * 128 + c];
    const float w1 = conv_w[(e + 1) * 128 + c];
    const float w2 = conv_w[(e + 2) * 128 + c];
    const float w3 = conv_w[(e + 3) * 128 + c];
#pragma unroll
    for (int j = 0; j < 8; j++) {
      const float4 qv = *(const float4*)(qs + (half * 8 + j) * 128 + e);
      acc[j] = fmaf(qv.x, w0, fmaf(qv.y, w1, fmaf(qv.z, w2, fmaf(qv.w, w3, acc[j]))));
    }
  }
  float* dst = qwx + ((size_t)n * 128 + c) * 128 + q0 + half * 8;
#pragma unroll
  for (int j = 0; j < 8; j++) dst[j] = acc[j];
  if (tid < 16) {
    float s = 0.f;
    for (int e = 0; e < 128; e += 4) {
      const float4 qv = *(const float4*)(qs + tid * 128 + e);
      const float4 bv = *(const float4*)(conv_b + e);
      s = fmaf(qv.x, bv.x, fmaf(qv.y, bv.y, fmaf(qv.z, bv.z, fmaf(qv.w, bv.w, s))));
    }
    qb[n * 128 + q0 + tid] = s;
  }
}

// ---------------- maps v4: conv v5 structure (depth-4 prefetch, 16 KB chunks) ----------------
__global__ __launch_bounds__(256) void maps_kernel(
    const float* __restrict__ x, const float* __restrict__ qwx, const float* __restrict__ qb,
    float* __restrict__ mout) {
  __shared__ float qlds[32 * 128];  // [c-chunk][q], 16 KB
  const int tid = threadIdx.x;
  const int lane = tid & 63, w = tid >> 6;
  const int n = blockIdx.y;
  const int hw0 = blockIdx.x * 128;
  const int hwi = 2 * lane;
  const int q0 = 32 * w;
  const float* xn = x + (size_t)n * CIN * HW + hw0 + hwi;
  float acc[2][32];
#pragma unroll
  for (int jj = 0; jj < 8; jj++) {
    const float4 b4 = *(const float4*)(qb + n * 128 + q0 + jj * 4);
    acc[0][jj*4+0] = b4.x; acc[1][jj*4+0] = b4.x;
    acc[0][jj*4+1] = b4.y; acc[1][jj*4+1] = b4.y;
    acc[0][jj*4+2] = b4.z; acc[1][jj*4+2] = b4.z;
    acc[0][jj*4+3] = b4.w; acc[1][jj*4+3] = b4.w;
  }
  float2 xv[4];
#pragma unroll
  for (int j = 0; j < 4; j++) xv[j] = *(const float2*)(xn + (size_t)j * HW);
  for (int ch = 0; ch < 4; ch++) {
    if (ch) __syncthreads();
    for (int idx = tid * 4; idx < 4096; idx += 1024)
      *(float4*)(qlds + idx) = *(const float4*)(qwx + (size_t)n * 16384 + ch * 4096 + idx);
    __syncthreads();
    for (int cg = 0; cg < 32; cg += 4) {
      float2 nx[4];
#pragma unroll
      for (int j = 0; j < 4; j++) {
        int cn = ch * 32 + cg + 4 + j;
        if (cn > 127) cn = 127;
        nx[j] = *(const float2*)(xn + (size_t)cn * HW);
      }
#pragma unroll
      for (int j = 0; j < 4; j++) {
        const float* ql = qlds + (cg + j) * 128 + q0;
#pragma unroll
        for (int jj = 0; jj < 8; jj++) {
          const float4 w4 = *(const float4*)(ql + jj * 4);
          acc[0][jj*4+0] = fmaf(w4.x, xv[j].x, acc[0][jj*4+0]); acc[1][jj*4+0] = fmaf(w4.x, xv[j].y, acc[1][jj*4+0]);
          acc[0][jj*4+1] = fmaf(w4.y, xv[j].x, acc[0][jj*4+1]); acc[1][jj*4+1] = fmaf(w4.y, xv[j].y, acc[1][jj*4+1]);
          acc[0][jj*4+2] = fmaf(w4.z, xv[j].x, acc[0][jj*4+2]); acc[1][jj*4+2] = fmaf(w4.z, xv[j].y, acc[1][jj*4+2]);
          acc[0][jj*4+3] = fmaf(w4.w, xv[j].x, acc[0][jj*4+3]); acc[1][jj*4+3] = fmaf(w4.w, xv[j].y, acc[1][jj*4+3]);
        }
      }
#pragma unroll
      for (int j = 0; j < 4; j++) xv[j] = nx[j];
    }
  }
  float* mb = mout + ((size_t)n * 128 + q0) * HW + hw0 + hwi;
#pragma unroll
  for (int jj = 0; jj < 32; jj++) {
    *(float2*)(mb + (size_t)jj * HW) = make_float2(acc[0][jj], acc[1][jj]);
  }
}

extern "C" void kernel_launch(void* const* d_in, const int* in_sizes, int n_in,
                              void* d_out, int out_size, void* d_ws, size_t ws_size,
                              hipStream_t stream) {
  const float* x      = (const float*)d_in[0];
  const float* conv_w = (const float*)d_in[1];
  const float* conv_b = (const float*)d_in[2];
  const float* n1_g   = (const float*)d_in[3];
  const float* n1_b   = (const float*)d_in[4];
  const float* qkv_w  = (const float*)d_in[5];
  const float* qkv_b  = (const float*)d_in[6];
  const float* proj_w = (const float*)d_in[7];
  const float* proj_b = (const float*)d_in[8];
  const float* n2_g   = (const float*)d_in[9];
  const float* n2_b   = (const float*)d_in[10];
  const float* fc1_w  = (const float*)d_in[11];
  const float* fc1_b  = (const float*)d_in[12];
  const float* fc2_w  = (const float*)d_in[13];
  const float* fc2_b  = (const float*)d_in[14];
  const float* r1_w   = (const float*)d_in[15];
  const float* r1_b   = (const float*)d_in[16];
  const float* r2_w   = (const float*)d_in[17];
  const float* r2_b   = (const float*)d_in[18];
  const float* r3_w   = (const float*)d_in[19];
  const float* r3_b   = (const float*)d_in[20];

  // Token residual stream (f32) lives in the d_out maps region; consumed before maps.
  float* out = (float*)d_out;
  float* tok = out + 512;

  // ws: bf16 weight copies (1.57 MB) + qwx/qb/headbuf
  char* ws = (char*)d_ws;
  short* wqkv = (short*)ws;                       // 4*384*128
  short* wproj = (short*)(ws + 393216);           // 4*128*128
  short* wfc1 = (short*)(ws + 524288);            // 4*512*128
  short* wfc2 = (short*)(ws + 1048576);           // 4*128*512
  float* qwx = (float*)(ws + 1572864);            // 2*128*128 f32
  float* qb = (float*)(ws + 1703936);             // 2*128
  float* headbuf = (float*)(ws + 1704960);        // 2*128
  // wconvT aliases the qwx region: used only by conv (early); qwx written by
  // qprep (late). 128*128 f32 = 64 KB <= qwx's 128 KB.
  float* wconvT = qwx;

  cast_bf16<<<196608 / 1024, 256, 0, stream>>>(qkv_w, wqkv, 196608);
  cast_bf16<<<65536 / 1024, 256, 0, stream>>>(proj_w, wproj, 65536);
  cast_bf16<<<262144 / 1024, 256, 0, stream>>>(fc1_w, wfc1, 262144);
  cast_bf16<<<262144 / 1024, 256, 0, stream>>>(fc2_w, wfc2, 262144);
  init_head<<<1, 256, 0, stream>>>(headbuf);
  transp_w<<<64, 256, 0, stream>>>(conv_w, wconvT);
  conv_kernel<<<dim3(600, 2), 256, 0, stream>>>(x, wconvT, conv_b, tok);
  for (int l = 0; l < 4; l++) {
    attn_kernel<<<NWIN, 256, 0, stream>>>(tok, n1_g, n1_b, wqkv, qkv_b, wproj, proj_b, l);
    mlp_kernel<<<2400, 512, 0, stream>>>(tok, n2_g, n2_b, wfc1, fc1_b, wfc2, fc2_b, l);
  }
  head_kernel<<<128, 256, 0, stream>>>(tok, headbuf);
  y_kernel<<<2, 256, 0, stream>>>(headbuf, r1_w, r1_b, r2_w, r2_b, r3_w, r3_b, out);
  qprep_kernel<<<16, 256, 0, stream>>>(tok, conv_w, conv_b, qwx, qb);
  maps_kernel<<<dim3(600, 2), 256, 0, stream>>>(x, qwx, qb, out + 512);
}

// Round 13
// 1280.887 us; speedup vs baseline: 1.1030x; 1.0374x over previous
//
#include <hip/hip_runtime.h>
#include <hip/hip_bf16.h>

typedef __hip_bfloat16 bf16;

// Problem constants
static constexpr int Nn = 2, CIN = 128, Hh = 240, Ww = 320, HW = 76800;
static constexpr int Cc = 128, HID = 512, DOUT = 256, WSQ = 49;
static constexpr int NWH = 35, NWW = 46, WPN = NWH * NWW;   // 1610 windows per image
static constexpr int NWIN = Nn * WPN;                        // 3220
static constexpr float SCALE = 0.17677669529663687f;         // 32^-0.5

// attn LDS geometry (v3): 4 head slices + xw/vT region = 25,856 shorts = 51,712 B
static constexpr int SLICE = 4160;   // shorts per head slice (q[52][40], k @2080)
static constexpr int KOFF  = 2080;
static constexpr int TRIM  = 52;     // q/k rows stored; >=49 masked downstream
static constexpr int XWOFF = 16640;  // 4*SLICE

typedef __attribute__((ext_vector_type(8))) short s8;   // 8 bf16 = one MFMA A/B frag
typedef __attribute__((ext_vector_type(4))) short s4;   // packed 4-bf16 LDS write
typedef __attribute__((ext_vector_type(2))) short s2;
typedef __attribute__((ext_vector_type(4))) float f4;   // MFMA accumulator

__device__ __forceinline__ short f2bf(float x) {
  union { bf16 b; short s; } u; u.b = __float2bfloat16(x); return u.s;
}

// tanh-form gelu via HW exp (numerics validated R8-R12, neutral perf vs erff).
__device__ __forceinline__ float gelu_f(float x) {
  const float u = 0.7978845608028654f * fmaf(0.044715f * x, x * x, x);
  const float e = __expf(2.f * u);
  const float t = fmaf(-2.f, __frcp_rn(e + 1.f), 1.f);   // tanh(u)
  return 0.5f * x * (1.f + t);
}

#define MFMA(a, b, c) __builtin_amdgcn_mfma_f32_16x16x32_bf16((a), (b), (c), 0, 0, 0)

// ---------------- fused prep: 4x weight cast + conv_w transpose + headbuf zero ----------------
// Replaces 6 serial prologue launches (4 cast_bf16 + transp_w + init_head)
// with one: blocks [0,768) cast 196608 float4 work-items over the concatenated
// {qkv, proj, fc1, fc2} ranges; blocks [768,832) transpose conv_w (16384
// elements); block 768 additionally zeroes headbuf.
__global__ __launch_bounds__(256) void prep_kernel(
    const float* __restrict__ qkv_w, const float* __restrict__ proj_w,
    const float* __restrict__ fc1_w, const float* __restrict__ fc2_w,
    const float* __restrict__ conv_w,
    short* __restrict__ wqkv, short* __restrict__ wproj,
    short* __restrict__ wfc1, short* __restrict__ wfc2,
    float* __restrict__ wT, float* __restrict__ headbuf) {
  const int bid = blockIdx.x, tid = threadIdx.x;
  if (bid < 768) {
    const int v = bid * 256 + tid;           // float4 index in [0, 196608)
    const float* src; short* dst; int off;
    if (v < 49152)       { src = qkv_w;  dst = wqkv;  off = v; }
    else if (v < 65536)  { src = proj_w; dst = wproj; off = v - 49152; }
    else if (v < 131072) { src = fc1_w;  dst = wfc1;  off = v - 65536; }
    else                 { src = fc2_w;  dst = wfc2;  off = v - 131072; }
    const float4 x = *(const float4*)(src + off * 4);
    s4 o; o[0] = f2bf(x.x); o[1] = f2bf(x.y); o[2] = f2bf(x.z); o[3] = f2bf(x.w);
    *(s4*)(dst + off * 4) = o;
  } else {
    const int idx = (bid - 768) * 256 + tid; // [0, 16384)
    const int c = idx >> 7, e = idx & 127;
    wT[c * 128 + e] = conv_w[e * 128 + c];
    if (bid == 768) headbuf[tid] = 0.f;
  }
}

// ---------------- 1x1 conv -> residual stream tok[n,hw,e] (f32, in d_out) ----------------
// v5: depth-4 x-prefetch + 16 KB LDS chunks. No forced min-occupancy.
__global__ __launch_bounds__(256) void conv_kernel(
    const float* __restrict__ x, const float* __restrict__ wT, const float* __restrict__ conv_b,
    float* __restrict__ tok) {
  __shared__ float wlds[32 * 128];  // [c-chunk][e], 16 KB
  const int tid = threadIdx.x;
  const int lane = tid & 63, w = tid >> 6;
  const int n = blockIdx.y;
  const int hw0 = blockIdx.x * 128;
  const int hwi = 2 * lane;         // thread owns hw pair (hwi, hwi+1)
  const int e0 = 32 * w;            // wave owns 32-wide e slice
  const float* xn = x + (size_t)n * CIN * HW + hw0 + hwi;
  float acc[2][32];
#pragma unroll
  for (int jj = 0; jj < 8; jj++) {
    const float4 b4 = *(const float4*)(conv_b + e0 + jj * 4);
    acc[0][jj*4+0] = b4.x; acc[1][jj*4+0] = b4.x;
    acc[0][jj*4+1] = b4.y; acc[1][jj*4+1] = b4.y;
    acc[0][jj*4+2] = b4.z; acc[1][jj*4+2] = b4.z;
    acc[0][jj*4+3] = b4.w; acc[1][jj*4+3] = b4.w;
  }
  float2 xv[4];
#pragma unroll
  for (int j = 0; j < 4; j++) xv[j] = *(const float2*)(xn + (size_t)j * HW);
  for (int ch = 0; ch < 4; ch++) {
    if (ch) __syncthreads();        // all waves done reading previous chunk
    for (int idx = tid * 4; idx < 4096; idx += 1024)
      *(float4*)(wlds + idx) = *(const float4*)(wT + ch * 4096 + idx);
    __syncthreads();
    for (int cg = 0; cg < 32; cg += 4) {
      float2 nx[4];
#pragma unroll
      for (int j = 0; j < 4; j++) {
        int cn = ch * 32 + cg + 4 + j;          // prefetch next group (may cross chunk)
        if (cn > 127) cn = 127;                 // tail clamp: dummy valid load
        nx[j] = *(const float2*)(xn + (size_t)cn * HW);
      }
#pragma unroll
      for (int j = 0; j < 4; j++) {
        const float* wl = wlds + (cg + j) * 128 + e0;
#pragma unroll
        for (int jj = 0; jj < 8; jj++) {
          const float4 w4 = *(const float4*)(wl + jj * 4);
          acc[0][jj*4+0] = fmaf(w4.x, xv[j].x, acc[0][jj*4+0]); acc[1][jj*4+0] = fmaf(w4.x, xv[j].y, acc[1][jj*4+0]);
          acc[0][jj*4+1] = fmaf(w4.y, xv[j].x, acc[0][jj*4+1]); acc[1][jj*4+1] = fmaf(w4.y, xv[j].y, acc[1][jj*4+1]);
          acc[0][jj*4+2] = fmaf(w4.z, xv[j].x, acc[0][jj*4+2]); acc[1][jj*4+2] = fmaf(w4.z, xv[j].y, acc[1][jj*4+2]);
          acc[0][jj*4+3] = fmaf(w4.w, xv[j].x, acc[0][jj*4+3]); acc[1][jj*4+3] = fmaf(w4.w, xv[j].y, acc[1][jj*4+3]);
        }
      }
#pragma unroll
      for (int j = 0; j < 4; j++) xv[j] = nx[j];
    }
  }
  float* tb0 = tok + ((size_t)n * HW + hw0 + hwi) * Cc + e0;
  float* tb1 = tb0 + Cc;
#pragma unroll
  for (int jj = 0; jj < 8; jj++) {
    *(float4*)(tb0 + jj * 4) = make_float4(acc[0][jj*4], acc[0][jj*4+1], acc[0][jj*4+2], acc[0][jj*4+3]);
    *(float4*)(tb1 + jj * 4) = make_float4(acc[1][jj*4], acc[1][jj*4+1], acc[1][jj*4+2], acc[1][jj*4+3]);
  }
}

// ---------------- fused window attention v3 (see R6 notes) ----------------
__global__ __launch_bounds__(256, 2) void attn_kernel(
    float* __restrict__ tok,
    const float* __restrict__ n1_g, const float* __restrict__ n1_b,
    const short* __restrict__ wqkv, const float* __restrict__ qkv_b,
    const short* __restrict__ wproj, const float* __restrict__ proj_b,
    int layer) {
  __shared__ __align__(16) short ms[25856];
  short* xwv = ms + XWOFF;

  const int tid = threadIdx.x;
  const int w = tid >> 6, lane = tid & 63;
  const int lq = lane >> 4, li = lane & 15;
  const int wi = blockIdx.x;
  const int n = wi / WPN;
  const int r0 = wi % WPN;
  const int wh = r0 / NWW, ww = r0 % NWW;

  const short* wqkv_l = wqkv + (size_t)layer * 384 * 128;
  const short* wproj_l = wproj + (size_t)layer * 128 * 128;

  // ---- Phase 1a: coalesced gather -> g32 f32 [49][128] (slice region) ----
  {
    float* g32 = (float*)ms;
    for (int idx = tid; idx < WSQ * 32; idx += 256) {
      const int t = idx >> 5, c4 = (idx & 31) * 4;
      const int hh = wh * 7 + t / 7, wv = ww * 7 + t % 7;
      float4 v = make_float4(0.f, 0.f, 0.f, 0.f);
      if (hh < Hh && wv < Ww)
        v = *(const float4*)(tok + ((size_t)n * HW + hh * Ww + wv) * Cc + c4);
      *(float4*)(g32 + t * 128 + c4) = v;
    }
    for (int idx = tid; idx < 15 * 136; idx += 256)
      xwv[(49 + idx / 136) * 136 + (idx % 136)] = 0;
    __syncthreads();
    // ---- Phase 1b: LayerNorm from LDS -> xw bf16 [64][136] ----
    for (int ti = w; ti < WSQ; ti += 4) {
      const int hh = wh * 7 + ti / 7, wv = ww * 7 + ti % 7;
      const bool valid = (hh < Hh) && (wv < Ww);
      const float2 v = *(const float2*)(g32 + ti * 128 + 2 * lane);
      float s = v.x + v.y, q = v.x * v.x + v.y * v.y;
#pragma unroll
      for (int m = 1; m < 64; m <<= 1) { s += __shfl_xor(s, m); q += __shfl_xor(q, m); }
      const float mean = s * (1.f / 128.f);
      const float rstd = rsqrtf(fmaxf(q * (1.f / 128.f) - mean * mean, 0.f) + 1e-5f);
      const int c = 2 * lane;
      float o0 = 0.f, o1 = 0.f;
      if (valid) {
        o0 = (v.x - mean) * rstd * n1_g[layer * Cc + c]     + n1_b[layer * Cc + c];
        o1 = (v.y - mean) * rstd * n1_g[layer * Cc + c + 1] + n1_b[layer * Cc + c + 1];
      }
      s2 pk; pk[0] = f2bf(o0); pk[1] = f2bf(o1);
      *(s2*)(xwv + ti * 136 + c) = pk;
    }
  }
  __syncthreads();   // g32 consumed; slices may now be overwritten by q/k

  // ---- Phase 2a: q,k transposed: D'[n][token] = wqkv . xw^T ----
  {
    const int n0 = 64 * w;
    f4 acc[4][4];
#pragma unroll
    for (int mt = 0; mt < 4; mt++)
#pragma unroll
      for (int nt = 0; nt < 4; nt++) acc[mt][nt] = f4{0.f, 0.f, 0.f, 0.f};
    for (int s = 0; s < 4; s++) {
      s8 a[4], b[4];
#pragma unroll
      for (int mt = 0; mt < 4; mt++)
        a[mt] = *(const s8*)(wqkv_l + (n0 + mt * 16 + li) * 128 + s * 32 + lq * 8);
#pragma unroll
      for (int nt = 0; nt < 4; nt++)
        b[nt] = *(const s8*)(xwv + (nt * 16 + li) * 136 + s * 32 + lq * 8);
#pragma unroll
      for (int mt = 0; mt < 4; mt++)
#pragma unroll
        for (int nt = 0; nt < 4; nt++) acc[mt][nt] = MFMA(a[mt], b[nt], acc[mt][nt]);
    }
    const bool isq = (w < 2);
    const float scl = isq ? SCALE : 1.f;
    const int koff = isq ? 0 : KOFF;
#pragma unroll
    for (int mt = 0; mt < 4; mt++) {
      const int nbase = n0 + mt * 16 + lq * 4;            // qkv output row (r=0)
      const int hsel = (isq ? nbase : (nbase - 128)) >> 5;
      const int d0 = nbase & 31;
      const float4 bb = *(const float4*)(qkv_b + layer * 384 + nbase);
#pragma unroll
      for (int nt = 0; nt < 4; nt++) {
        const int tokn = nt * 16 + li;
        if (tokn < TRIM) {   // rows >= TRIM trimmed (masked downstream)
          s4 pk;
          pk[0] = f2bf((acc[mt][nt][0] + bb.x) * scl);
          pk[1] = f2bf((acc[mt][nt][1] + bb.y) * scl);
          pk[2] = f2bf((acc[mt][nt][2] + bb.z) * scl);
          pk[3] = f2bf((acc[mt][nt][3] + bb.w) * scl);
          *(s4*)(ms + hsel * SLICE + koff + tokn * 40 + d0) = pk;
        }
      }
    }
  }

  // ---- Phase 2b: v straight: D[token][n] = xw . wqkv_v^T ; export vT[d][token] ----
  {
    const int n0v = 32 * w;
    f4 acc2[4][2];
#pragma unroll
    for (int mt = 0; mt < 4; mt++)
#pragma unroll
      for (int nt = 0; nt < 2; nt++) acc2[mt][nt] = f4{0.f, 0.f, 0.f, 0.f};
    for (int s = 0; s < 4; s++) {
      s8 a[4], b[2];
#pragma unroll
      for (int mt = 0; mt < 4; mt++)
        a[mt] = *(const s8*)(xwv + (mt * 16 + li) * 136 + s * 32 + lq * 8);
#pragma unroll
      for (int nt = 0; nt < 2; nt++)
        b[nt] = *(const s8*)(wqkv_l + (256 + n0v + nt * 16 + li) * 128 + s * 32 + lq * 8);
#pragma unroll
      for (int mt = 0; mt < 4; mt++)
#pragma unroll
        for (int nt = 0; nt < 2; nt++) acc2[mt][nt] = MFMA(a[mt], b[nt], acc2[mt][nt]);
    }
    __syncthreads();  // all xw reads + all q/k writes complete
#pragma unroll
    for (int nt = 0; nt < 2; nt++) {
      const int d = n0v + nt * 16 + li;
      const float bv = qkv_b[layer * 384 + 256 + d];
#pragma unroll
      for (int mt = 0; mt < 4; mt++) {
        const int m0 = mt * 16 + lq * 4;
        s4 pk;
        pk[0] = f2bf(acc2[mt][nt][0] + bv);
        pk[1] = f2bf(acc2[mt][nt][1] + bv);
        pk[2] = f2bf(acc2[mt][nt][2] + bv);
        pk[3] = f2bf(acc2[mt][nt][3] + bv);
        *(s4*)(xwv + d * 72 + m0) = pk;
      }
    }
  }

  // ---- Phase 3: per-head (wave = head): S^T = K.Q^T -> softmax -> O^T = V^T.P^T ----
  {
    short* qbase = ms + w * SLICE;
    short* kbase = qbase + KOFF;
    s8 ak[4], bq[4];
#pragma unroll
    for (int kt = 0; kt < 4; kt++) ak[kt] = *(const s8*)(kbase + (kt * 16 + li) * 40 + lq * 8);
#pragma unroll
    for (int qt = 0; qt < 4; qt++) bq[qt] = *(const s8*)(qbase + (qt * 16 + li) * 40 + lq * 8);
    f4 sc[4][4];
#pragma unroll
    for (int kt = 0; kt < 4; kt++)
#pragma unroll
      for (int qt = 0; qt < 4; qt++) sc[kt][qt] = f4{0.f, 0.f, 0.f, 0.f};
#pragma unroll
    for (int kt = 0; kt < 4; kt++)
#pragma unroll
      for (int qt = 0; qt < 4; qt++) sc[kt][qt] = MFMA(ak[kt], bq[qt], sc[kt][qt]);
#pragma unroll
    for (int kt = 0; kt < 4; kt++)
#pragma unroll
      for (int r = 0; r < 4; r++)
        if (kt * 16 + lq * 4 + r >= WSQ) {
#pragma unroll
          for (int qt = 0; qt < 4; qt++) sc[kt][qt][r] = -1e30f;
        }
    float inv[4];
#pragma unroll
    for (int qt = 0; qt < 4; qt++) {
      float m = -1e30f;
#pragma unroll
      for (int kt = 0; kt < 4; kt++)
#pragma unroll
        for (int r = 0; r < 4; r++) m = fmaxf(m, sc[kt][qt][r]);
      m = fmaxf(m, __shfl_xor(m, 16));
      m = fmaxf(m, __shfl_xor(m, 32));
      float ssum = 0.f;
#pragma unroll
      for (int kt = 0; kt < 4; kt++)
#pragma unroll
        for (int r = 0; r < 4; r++) {
          const float e = __expf(sc[kt][qt][r] - m);
          sc[kt][qt][r] = e; ssum += e;
        }
      ssum += __shfl_xor(ssum, 16);
      ssum += __shfl_xor(ssum, 32);
      inv[qt] = 1.f / ssum;
    }
#pragma unroll
    for (int qt = 0; qt < 4; qt++) {
      const int qq = qt * 16 + li;
      if (qq < TRIM) {
#pragma unroll
        for (int kt = 0; kt < 4; kt++) {
          s4 pk;
          pk[0] = f2bf(sc[kt][qt][0] * inv[qt]);
          pk[1] = f2bf(sc[kt][qt][1] * inv[qt]);
          pk[2] = f2bf(sc[kt][qt][2] * inv[qt]);
          pk[3] = f2bf(sc[kt][qt][3] * inv[qt]);
          *(s4*)(qbase + qq * 72 + kt * 16 + lq * 4) = pk;
        }
      }
    }
    f4 ov[2][4];
#pragma unroll
    for (int dt = 0; dt < 2; dt++)
#pragma unroll
      for (int qt = 0; qt < 4; qt++) ov[dt][qt] = f4{0.f, 0.f, 0.f, 0.f};
    for (int s = 0; s < 2; s++) {
      s8 av[2], bp[4];
#pragma unroll
      for (int dt = 0; dt < 2; dt++)
        av[dt] = *(const s8*)(xwv + (w * 32 + dt * 16 + li) * 72 + s * 32 + lq * 8);
#pragma unroll
      for (int qt = 0; qt < 4; qt++)
        bp[qt] = *(const s8*)(qbase + (qt * 16 + li) * 72 + s * 32 + lq * 8);
#pragma unroll
      for (int dt = 0; dt < 2; dt++)
#pragma unroll
        for (int qt = 0; qt < 4; qt++) ov[dt][qt] = MFMA(av[dt], bp[qt], ov[dt][qt]);
    }
    short* ohb = qbase;
#pragma unroll
    for (int dt = 0; dt < 2; dt++) {
      const int dl0 = dt * 16 + lq * 4;
#pragma unroll
      for (int qt = 0; qt < 4; qt++) {
        const int tokn = qt * 16 + li;
        s4 pk;
        pk[0] = f2bf(ov[dt][qt][0]);
        pk[1] = f2bf(ov[dt][qt][1]);
        pk[2] = f2bf(ov[dt][qt][2]);
        pk[3] = f2bf(ov[dt][qt][3]);
        *(s4*)(ohb + tokn * 40 + dl0) = pk;
      }
    }
  }
  __syncthreads();

  // ---- Phase 4: proj straight: D[token][c] = o . wproj^T ; staged residual RMW ----
  {
    const int n0p = 32 * w;
    f4 pa[4][2];
#pragma unroll
    for (int mt = 0; mt < 4; mt++)
#pragma unroll
      for (int nt = 0; nt < 2; nt++) pa[mt][nt] = f4{0.f, 0.f, 0.f, 0.f};
    for (int s = 0; s < 4; s++) {
      s8 ao[4], bw[2];
#pragma unroll
      for (int mt = 0; mt < 4; mt++)
        ao[mt] = *(const s8*)(ms + s * SLICE + (mt * 16 + li) * 40 + lq * 8);
#pragma unroll
      for (int nt = 0; nt < 2; nt++)
        bw[nt] = *(const s8*)(wproj_l + (n0p + nt * 16 + li) * 128 + s * 32 + lq * 8);
#pragma unroll
      for (int mt = 0; mt < 4; mt++)
#pragma unroll
        for (int nt = 0; nt < 2; nt++) pa[mt][nt] = MFMA(ao[mt], bw[nt], pa[mt][nt]);
    }
    __syncthreads();  // all o reads done everywhere; ms fully dead -> res
    float* res = (float*)ms;   // [64][132] f32 = 33,792 B
#pragma unroll
    for (int nt = 0; nt < 2; nt++) {
      const int c = n0p + nt * 16 + li;
#pragma unroll
      for (int mt = 0; mt < 4; mt++) {
#pragma unroll
        for (int r = 0; r < 4; r++) {
          const int m = mt * 16 + lq * 4 + r;
          res[m * 132 + c] = pa[mt][nt][r];
        }
      }
    }
    __syncthreads();
    for (int idx = tid; idx < WSQ * 32; idx += 256) {
      const int t = idx >> 5, c4 = (idx & 31) * 4;
      const int hh = wh * 7 + t / 7, wv = ww * 7 + t % 7;
      if (hh < Hh && wv < Ww) {
        float* p = tok + ((size_t)n * HW + hh * Ww + wv) * Cc + c4;
        const float4 g = *(const float4*)p;
        const float4 r4 = *(const float4*)(res + t * 132 + c4);
        const float4 pb4 = *(const float4*)(proj_b + layer * 128 + c4);
        *(float4*)p = make_float4(g.x + r4.x + pb4.x, g.y + r4.y + pb4.y,
                                  g.z + r4.z + pb4.z, g.w + r4.w + pb4.w);
      }
    }
  }
}

// ---------------- fused MLP v7: 512 threads (8 waves), 64 tok/block ----------------
// Best measured mlp (R12: 140.0 us, Occ 54%). Occupancy-doubling experiment
// proved mlp is phase/throughput-bound, not wave-latency-bound; structure kept.
__global__ __launch_bounds__(512) void mlp_kernel(
    float* __restrict__ tok,
    const float* __restrict__ n2_g, const float* __restrict__ n2_b,
    const short* __restrict__ wfc1, const float* __restrict__ fc1_b,
    const short* __restrict__ wfc2, const float* __restrict__ fc2_b,
    int layer) {
  __shared__ __align__(16) short lnb[64 * 136];      // LN'd tokens bf16 [64][136]
  __shared__ __align__(16) short hbuf[2][64 * 136];  // hid slice bf16 [tok][128] (dbuf)

  const int tid = threadIdx.x;
  const int w = tid >> 6, lane = tid & 63;           // w in [0,8)
  const int lq = lane >> 4, li = lane & 15;
  const int t0 = blockIdx.x * 64;
  const short* wfc1_l = wfc1 + (size_t)layer * 512 * 128;
  const short* wfc2_l = wfc2 + (size_t)layer * 128 * 512;

  // ---- Phase 1: LN -> lnb bf16 (wave w owns tokens [8w, 8w+8)) ----
#pragma unroll
  for (int i = 0; i < 8; i++) {
    const int tl = w * 8 + i;
    const float2 v = *(const float2*)(tok + (size_t)(t0 + tl) * Cc + 2 * lane);
    float s = v.x + v.y, q = v.x * v.x + v.y * v.y;
#pragma unroll
    for (int m = 1; m < 64; m <<= 1) { s += __shfl_xor(s, m); q += __shfl_xor(q, m); }
    const float mean = s * (1.f / 128.f);
    const float rstd = rsqrtf(fmaxf(q * (1.f / 128.f) - mean * mean, 0.f) + 1e-5f);
    const int c = 2 * lane;
    s2 pk;
    pk[0] = f2bf((v.x - mean) * rstd * n2_g[layer * Cc + c]     + n2_b[layer * Cc + c]);
    pk[1] = f2bf((v.y - mean) * rstd * n2_g[layer * Cc + c + 1] + n2_b[layer * Cc + c + 1]);
    *(s2*)(lnb + tl * 136 + c) = pk;
  }
  __syncthreads();

  // fc2 output accumulators: wave w owns c-rows [16w, 16w+16), all 64 tokens.
  f4 acc2[4];
#pragma unroll
  for (int nt = 0; nt < 4; nt++) acc2[nt] = f4{0.f, 0.f, 0.f, 0.f};
  const int c0 = 16 * w;

  // ---- Rounds: fc1 h-slice [128s,128s+128) -> gelu -> hbuf -> fc2 partial ----
  for (int s = 0; s < 4; s++) {
    f4 acc1[4];
#pragma unroll
    for (int nt = 0; nt < 4; nt++) acc1[nt] = f4{0.f, 0.f, 0.f, 0.f};
    const int hbase = 128 * s + 16 * w;   // wave w's 16 h-rows this round
    for (int kc = 0; kc < 4; kc++) {
      const s8 a = *(const s8*)(wfc1_l + (hbase + li) * 128 + kc * 32 + lq * 8);
      s8 b[4];
#pragma unroll
      for (int nt = 0; nt < 4; nt++)
        b[nt] = *(const s8*)(lnb + (nt * 16 + li) * 136 + kc * 32 + lq * 8);
#pragma unroll
      for (int nt = 0; nt < 4; nt++) acc1[nt] = MFMA(a, b[nt], acc1[nt]);
    }
    short* hb = hbuf[s & 1];
    {
      const int hl0 = 16 * w + lq * 4;                 // h_local in [0,128)
      const float4 bb = *(const float4*)(fc1_b + layer * HID + 128 * s + hl0);
#pragma unroll
      for (int nt = 0; nt < 4; nt++) {
        const int tokn = nt * 16 + li;
        s4 pk;
        pk[0] = f2bf(gelu_f(acc1[nt][0] + bb.x));
        pk[1] = f2bf(gelu_f(acc1[nt][1] + bb.y));
        pk[2] = f2bf(gelu_f(acc1[nt][2] + bb.z));
        pk[3] = f2bf(gelu_f(acc1[nt][3] + bb.w));
        *(s4*)(hb + tokn * 136 + hl0) = pk;
      }
    }
    __syncthreads();  // hbuf[s&1] complete; safe vs round s+2 by barrier s+1
    for (int kc = 0; kc < 4; kc++) {
      const s8 a = *(const s8*)(wfc2_l + (c0 + li) * 512 + s * 128 + kc * 32 + lq * 8);
      s8 b[4];
#pragma unroll
      for (int nt = 0; nt < 4; nt++)
        b[nt] = *(const s8*)(hb + (nt * 16 + li) * 136 + kc * 32 + lq * 8);
#pragma unroll
      for (int nt = 0; nt < 4; nt++) acc2[nt] = MFMA(a, b[nt], acc2[nt]);
    }
  }

  // ---- Epilogue: residual RMW, float4 per nt; wave w covers c [16w,16w+16) ----
  {
    const int cb = c0 + lq * 4;
    const float4 bb = *(const float4*)(fc2_b + layer * Cc + cb);
#pragma unroll
    for (int nt = 0; nt < 4; nt++) {
      const int tokn = nt * 16 + li;
      float* p = tok + (size_t)(t0 + tokn) * Cc + cb;
      const float4 g = *(const float4*)p;
      *(float4*)p = make_float4(g.x + acc2[nt][0] + bb.x,
                                g.y + acc2[nt][1] + bb.y,
                                g.z + acc2[nt][2] + bb.z,
                                g.w + acc2[nt][3] + bb.w);
    }
  }
}

// ---------------- head mean v2: 256 blocks (was 128 = half the CUs idle) ----------------
__global__ __launch_bounds__(256) void head_kernel(const float* __restrict__ tok,
                                                   float* __restrict__ headbuf) {
  const int n = blockIdx.x >> 7, slice = blockIdx.x & 127;
  const int c = threadIdx.x & 127, half = threadIdx.x >> 7;
  const float* base = tok + ((size_t)n * HW + slice * 600 + half * 300) * Cc + c;
  float s = 0.f;
  for (int i = 0; i < 300; i++) s += base[(size_t)i * Cc];
  atomicAdd(&headbuf[n * 128 + c], s * (1.f / 76800.f));
}

// ---------------- y head MLP ----------------
__global__ __launch_bounds__(256) void y_kernel(
    const float* __restrict__ headbuf,
    const float* __restrict__ r1_w, const float* __restrict__ r1_b,
    const float* __restrict__ r2_w, const float* __restrict__ r2_b,
    const float* __restrict__ r3_w, const float* __restrict__ r3_b,
    float* __restrict__ yout) {
  __shared__ float hb[128], y1[256], y2[256], red4[4];
  const int tid = threadIdx.x;
  const int n = blockIdx.x;
  if (tid < 128) hb[tid] = headbuf[n * 128 + tid];
  __syncthreads();
  {
    float s = r1_b[tid];
    const float* w = r1_w + (size_t)tid * 128;
    for (int c = 0; c < 128; c += 4) {
      const float4 w4 = *(const float4*)(w + c);
      s = fmaf(w4.x, hb[c], s); s = fmaf(w4.y, hb[c+1], s);
      s = fmaf(w4.z, hb[c+2], s); s = fmaf(w4.w, hb[c+3], s);
    }
    y1[tid] = s >= 0.f ? s : 0.01f * s;
  }
  __syncthreads();
  {
    float s = r2_b[tid];
    const float* w = r2_w + (size_t)tid * 256;
    for (int c = 0; c < 256; c += 4) {
      const float4 w4 = *(const float4*)(w + c);
      s = fmaf(w4.x, y1[c], s); s = fmaf(w4.y, y1[c+1], s);
      s = fmaf(w4.z, y1[c+2], s); s = fmaf(w4.w, y1[c+3], s);
    }
    y2[tid] = s >= 0.f ? s : 0.01f * s;
  }
  __syncthreads();
  float v;
  {
    float s = r3_b[tid];
    const float* w = r3_w + (size_t)tid * 256;
    for (int c = 0; c < 256; c += 4) {
      const float4 w4 = *(const float4*)(w + c);
      s = fmaf(w4.x, y2[c], s); s = fmaf(w4.y, y2[c+1], s);
      s = fmaf(w4.z, y2[c+2], s); s = fmaf(w4.w, y2[c+3], s);
    }
    v = (s > 0.f ? s : 0.f) + 0.1f;
  }
  float t = v;
#pragma unroll
  for (int m = 1; m < 64; m <<= 1) t += __shfl_xor(t, m);
  if ((tid & 63) == 0) red4[tid >> 6] = t;
  __syncthreads();
  const float tot = red4[0] + red4[1] + red4[2] + red4[3];
  yout[n * DOUT + tid] = v / tot;
}

// ---------------- maps prep: fold queries into conv weights ----------------
__global__ __launch_bounds__(256) void qprep_kernel(
    const float* __restrict__ tok, const float* __restrict__ conv_w, const float* __restrict__ conv_b,
    float* __restrict__ qwx, float* __restrict__ qb) {
  __shared__ float qs[16 * 128];  // [q_local][e]
  const int tid = threadIdx.x;
  const int n = blockIdx.x >> 3, g = blockIdx.x & 7;
  const int q0 = g * 16;
  for (int idx = tid; idx < 2048; idx += 256)
    qs[idx] = tok[((size_t)n * HW + q0 + (idx >> 7)) * Cc + (idx & 127)];
  __syncthreads();
  const int c = tid & 127, half = tid >> 7;
  float acc[8];
#pragma unroll
  for (int j = 0; j < 8; j++) acc[j] = 0.f;
  for (int e = 0; e < 128; e += 4) {
    const float w0 = conv_w[(e + 0) * 128 + c];
    const float w1 = conv_w[(e + 1) * 128 + c];
    const float w2 = conv_w[(e + 2) * 128 + c];
    const float w3 = conv_w[(e + 3) * 128 + c];
#pragma unroll
    for (int j = 0; j < 8; j++) {
      const float4 qv = *(const float4*)(qs + (half * 8 + j) * 128 + e);
      acc[j] = fmaf(qv.x, w0, fmaf(qv.y, w1, fmaf(qv.z, w2, fmaf(qv.w, w3, acc[j]))));
    }
  }
  float* dst = qwx + ((size_t)n * 128 + c) * 128 + q0 + half * 8;
#pragma unroll
  for (int j = 0; j < 8; j++) dst[j] = acc[j];
  if (tid < 16) {
    float s = 0.f;
    for (int e = 0; e < 128; e += 4) {
      const float4 qv = *(const float4*)(qs + tid * 128 + e);
      const float4 bv = *(const float4*)(conv_b + e);
      s = fmaf(qv.x, bv.x, fmaf(qv.y, bv.y, fmaf(qv.z, bv.z, fmaf(qv.w, bv.w, s))));
    }
    qb[n * 128 + q0 + tid] = s;
  }
}

// ---------------- maps v4: conv v5 structure (depth-4 prefetch, 16 KB chunks) ----------------
__global__ __launch_bounds__(256) void maps_kernel(
    const float* __restrict__ x, const float* __restrict__ qwx, const float* __restrict__ qb,
    float* __restrict__ mout) {
  __shared__ float qlds[32 * 128];  // [c-chunk][q], 16 KB
  const int tid = threadIdx.x;
  const int lane = tid & 63, w = tid >> 6;
  const int n = blockIdx.y;
  const int hw0 = blockIdx.x * 128;
  const int hwi = 2 * lane;
  const int q0 = 32 * w;
  const float* xn = x + (size_t)n * CIN * HW + hw0 + hwi;
  float acc[2][32];
#pragma unroll
  for (int jj = 0; jj < 8; jj++) {
    const float4 b4 = *(const float4*)(qb + n * 128 + q0 + jj * 4);
    acc[0][jj*4+0] = b4.x; acc[1][jj*4+0] = b4.x;
    acc[0][jj*4+1] = b4.y; acc[1][jj*4+1] = b4.y;
    acc[0][jj*4+2] = b4.z; acc[1][jj*4+2] = b4.z;
    acc[0][jj*4+3] = b4.w; acc[1][jj*4+3] = b4.w;
  }
  float2 xv[4];
#pragma unroll
  for (int j = 0; j < 4; j++) xv[j] = *(const float2*)(xn + (size_t)j * HW);
  for (int ch = 0; ch < 4; ch++) {
    if (ch) __syncthreads();
    for (int idx = tid * 4; idx < 4096; idx += 1024)
      *(float4*)(qlds + idx) = *(const float4*)(qwx + (size_t)n * 16384 + ch * 4096 + idx);
    __syncthreads();
    for (int cg = 0; cg < 32; cg += 4) {
      float2 nx[4];
#pragma unroll
      for (int j = 0; j < 4; j++) {
        int cn = ch * 32 + cg + 4 + j;
        if (cn > 127) cn = 127;
        nx[j] = *(const float2*)(xn + (size_t)cn * HW);
      }
#pragma unroll
      for (int j = 0; j < 4; j++) {
        const float* ql = qlds + (cg + j) * 128 + q0;
#pragma unroll
        for (int jj = 0; jj < 8; jj++) {
          const float4 w4 = *(const float4*)(ql + jj * 4);
          acc[0][jj*4+0] = fmaf(w4.x, xv[j].x, acc[0][jj*4+0]); acc[1][jj*4+0] = fmaf(w4.x, xv[j].y, acc[1][jj*4+0]);
          acc[0][jj*4+1] = fmaf(w4.y, xv[j].x, acc[0][jj*4+1]); acc[1][jj*4+1] = fmaf(w4.y, xv[j].y, acc[1][jj*4+1]);
          acc[0][jj*4+2] = fmaf(w4.z, xv[j].x, acc[0][jj*4+2]); acc[1][jj*4+2] = fmaf(w4.z, xv[j].y, acc[1][jj*4+2]);
          acc[0][jj*4+3] = fmaf(w4.w, xv[j].x, acc[0][jj*4+3]); acc[1][jj*4+3] = fmaf(w4.w, xv[j].y, acc[1][jj*4+3]);
        }
      }
#pragma unroll
      for (int j = 0; j < 4; j++) xv[j] = nx[j];
    }
  }
  float* mb = mout + ((size_t)n * 128 + q0) * HW + hw0 + hwi;
#pragma unroll
  for (int jj = 0; jj < 32; jj++) {
    *(float2*)(mb + (size_t)jj * HW) = make_float2(acc[0][jj], acc[1][jj]);
  }
}

extern "C" void kernel_launch(void* const* d_in, const int* in_sizes, int n_in,
                              void* d_out, int out_size, void* d_ws, size_t ws_size,
                              hipStream_t stream) {
  const float* x      = (const float*)d_in[0];
  const float* conv_w = (const float*)d_in[1];
  const float* conv_b = (const float*)d_in[2];
  const float* n1_g   = (const float*)d_in[3];
  const float* n1_b   = (const float*)d_in[4];
  const float* qkv_w  = (const float*)d_in[5];
  const float* qkv_b  = (const float*)d_in[6];
  const float* proj_w = (const float*)d_in[7];
  const float* proj_b = (const float*)d_in[8];
  const float* n2_g   = (const float*)d_in[9];
  const float* n2_b   = (const float*)d_in[10];
  const float* fc1_w  = (const float*)d_in[11];
  const float* fc1_b  = (const float*)d_in[12];
  const float* fc2_w  = (const float*)d_in[13];
  const float* fc2_b  = (const float*)d_in[14];
  const float* r1_w   = (const float*)d_in[15];
  const float* r1_b   = (const float*)d_in[16];
  const float* r2_w   = (const float*)d_in[17];
  const float* r2_b   = (const float*)d_in[18];
  const float* r3_w   = (const float*)d_in[19];
  const float* r3_b   = (const float*)d_in[20];

  // Token residual stream (f32) lives in the d_out maps region; consumed before maps.
  float* out = (float*)d_out;
  float* tok = out + 512;

  // ws: bf16 weight copies (1.57 MB) + qwx/qb/headbuf
  char* ws = (char*)d_ws;
  short* wqkv = (short*)ws;                       // 4*384*128
  short* wproj = (short*)(ws + 393216);           // 4*128*128
  short* wfc1 = (short*)(ws + 524288);            // 4*512*128
  short* wfc2 = (short*)(ws + 1048576);           // 4*128*512
  float* qwx = (float*)(ws + 1572864);            // 2*128*128 f32
  float* qb = (float*)(ws + 1703936);             // 2*128
  float* headbuf = (float*)(ws + 1704960);        // 2*128
  // wconvT aliases the qwx region: used only by conv (early); qwx written by
  // qprep (late). 128*128 f32 = 64 KB <= qwx's 128 KB.
  float* wconvT = qwx;

  prep_kernel<<<832, 256, 0, stream>>>(qkv_w, proj_w, fc1_w, fc2_w, conv_w,
                                       wqkv, wproj, wfc1, wfc2, wconvT, headbuf);
  conv_kernel<<<dim3(600, 2), 256, 0, stream>>>(x, wconvT, conv_b, tok);
  for (int l = 0; l < 4; l++) {
    attn_kernel<<<NWIN, 256, 0, stream>>>(tok, n1_g, n1_b, wqkv, qkv_b, wproj, proj_b, l);
    mlp_kernel<<<2400, 512, 0, stream>>>(tok, n2_g, n2_b, wfc1, fc1_b, wfc2, fc2_b, l);
  }
  head_kernel<<<256, 256, 0, stream>>>(tok, headbuf);
  y_kernel<<<2, 256, 0, stream>>>(headbuf, r1_w, r1_b, r2_w, r2_b, r3_w, r3_b, out);
  qprep_kernel<<<16, 256, 0, stream>>>(tok, conv_w, conv_b, qwx, qb);
  maps_kernel<<<dim3(600, 2), 256, 0, stream>>>(x, qwx, qb, out + 512);
}